// Round 1
// baseline (479.993 us; speedup 1.0000x reference)
//
#include <hip/hip_runtime.h>

// LFMA adapter: out = x@W_base^T + b + x @ (alpha * Re(ifft2(scatter(c, mask_idx))))
// Factored: never materialize Delta_W.
//   X[t,k1] = sum_m x[t,m] e^{+2pi i m k1/4096}          (kernel A, per-row DFT-4096)
//   Y[t,k2] = sum_{nz (k1,k2,c)} c * X[t,k1]             (bucketed sparse, kernels B1-B4)
//   out2[t,n] = SCALE * Re( sum_k2 Y[t,k2] e^{+2pi i n k2/4096} )   (kernel C)
//   SCALE = alpha / (4096*4096)
// DFT-4096 done as 64x64 two-step with brute-force DFT-64 (no bit reversal).

#define TWO_PI 6.28318530717958647692f
constexpr int NROW = 128;          // 2*64 rows of x
constexpr float SCALE_A = 16.0f / 16777216.0f;

// ---------------- Kernel A: X^T[k][t] (transposed store for coalesced spmm gathers)
__global__ __launch_bounds__(1024) void dft_rows_x(const float* __restrict__ x,
                                                   float2* __restrict__ XT) {
  __shared__ float xs[4096];
  __shared__ float br[4096], bi[4096];
  __shared__ float2 w64[64];
  const int t = blockIdx.x, tid = threadIdx.x;
  const float* xrow = x + (size_t)t * 4096;
#pragma unroll
  for (int l = 0; l < 4; ++l) xs[tid + 1024 * l] = xrow[tid + 1024 * l];
  if (tid < 64) {
    float s, c; __sincosf(TWO_PI * (float)tid * (1.0f / 64.0f), &s, &c);
    w64[tid] = make_float2(c, s);          // W64^j = e^{+2pi i j/64}
  }
  __syncthreads();
  // phase 1: B[m1*64+k1] = (sum_m2 xs[m1+64*m2] W64^{m2 k1}) * W4096^{m1 k1}
#pragma unroll
  for (int l = 0; l < 4; ++l) {
    int o = tid + 1024 * l, m1 = o >> 6, k1 = o & 63;
    float ar = 0.f, ai = 0.f;
    for (int m2 = 0; m2 < 64; ++m2) {
      float xv = xs[m1 + (m2 << 6)];       // wave-uniform -> broadcast
      float2 w = w64[(m2 * k1) & 63];
      ar = fmaf(xv, w.x, ar); ai = fmaf(xv, w.y, ai);
    }
    float s, c; __sincosf((float)((m1 * k1) & 4095) * (TWO_PI / 4096.0f), &s, &c);
    br[o] = ar * c - ai * s;
    bi[o] = ar * s + ai * c;
  }
  __syncthreads();
  // phase 2: X[k1+64*k2] = sum_m1 B[m1*64+k1] W64^{m1 k2}
#pragma unroll
  for (int l = 0; l < 4; ++l) {
    int o = tid + 1024 * l, k1 = o & 63, k2 = o >> 6;
    float xr = 0.f, xi = 0.f;
    for (int m1 = 0; m1 < 64; ++m1) {
      float brv = br[(m1 << 6) + k1], biv = bi[(m1 << 6) + k1];
      float2 w = w64[(m1 * k2) & 63];
      xr += brv * w.x - biv * w.y;
      xi += brv * w.y + biv * w.x;
    }
    XT[(size_t)o * NROW + t] = make_float2(xr, xi);
  }
}

// ---------------- B1: histogram of k2 = idx & 4095
__global__ void histo(const int* __restrict__ idx, int K, int* __restrict__ count) {
  int j = blockIdx.x * 256 + threadIdx.x;
  if (j < K) atomicAdd(&count[idx[j] & 4095], 1);
}

// ---------------- B2: exclusive scan over 4096 counts (single block)
__global__ __launch_bounds__(1024) void scan4096(const int* __restrict__ count,
                                                 int* __restrict__ off) {
  __shared__ int s[4096];
  int tid = threadIdx.x;
#pragma unroll
  for (int l = 0; l < 4; ++l) s[tid + 1024 * l] = count[tid + 1024 * l];
  __syncthreads();
  for (int d = 1; d < 4096; d <<= 1) {
    int v[4];
#pragma unroll
    for (int l = 0; l < 4; ++l) {
      int i = tid + 1024 * l;
      v[l] = s[i] + ((i >= d) ? s[i - d] : 0);
    }
    __syncthreads();
#pragma unroll
    for (int l = 0; l < 4; ++l) s[tid + 1024 * l] = v[l];
    __syncthreads();
  }
#pragma unroll
  for (int l = 0; l < 4; ++l) {
    int i = tid + 1024 * l;
    off[i] = s[i] - count[i];                // exclusive
  }
}

// ---------------- B3: scatter nonzeros into column buckets
__global__ void scatter_nz(const int* __restrict__ idx, const float* __restrict__ cre,
                           const float* __restrict__ cim, int K,
                           const int* __restrict__ off, int* __restrict__ cursor,
                           float4* __restrict__ bucket) {
  int j = blockIdx.x * 256 + threadIdx.x;
  if (j < K) {
    int p = idx[j];
    int k2 = p & 4095, k1 = p >> 12;
    int pos = off[k2] + atomicAdd(&cursor[k2], 1);
    bucket[pos] = make_float4(__int_as_float(k1), cre[j], cim[j], 0.f);
  }
}

// ---------------- B4: per-column sparse accumulate  Y[t][k2] = sum c * X[t,k1]
__global__ __launch_bounds__(128) void spmm_col(const float4* __restrict__ bucket,
                                                const int* __restrict__ off,
                                                const int* __restrict__ count,
                                                const float2* __restrict__ XT,
                                                float2* __restrict__ Y) {
  int k2 = blockIdx.x;
  int t = threadIdx.x;
  int s = off[k2], n = count[k2];
  float ar = 0.f, ai = 0.f;
  for (int j = 0; j < n; ++j) {
    float4 e = bucket[s + j];                   // wave-uniform broadcast
    int k1 = __float_as_int(e.x);
    float2 xv = XT[(size_t)k1 * NROW + t];      // coalesced 128x8B gather (L2)
    ar += e.y * xv.x - e.z * xv.y;
    ai += e.y * xv.y + e.z * xv.x;
  }
  Y[(size_t)t * 4096 + k2] = make_float2(ar, ai);
}

// ---------------- Kernel C: out[t][n] += SCALE * Re(DFT-4096 of Y row)
__global__ __launch_bounds__(1024) void dft_rows_y(const float2* __restrict__ Y,
                                                   float* __restrict__ out) {
  __shared__ float ysr[4096], ysi[4096];
  __shared__ float br[4096], bi[4096];
  __shared__ float2 w64[64];
  const int t = blockIdx.x, tid = threadIdx.x;
  const float2* yrow = Y + (size_t)t * 4096;
#pragma unroll
  for (int l = 0; l < 4; ++l) {
    float2 v = yrow[tid + 1024 * l];
    ysr[tid + 1024 * l] = v.x; ysi[tid + 1024 * l] = v.y;
  }
  if (tid < 64) {
    float s, c; __sincosf(TWO_PI * (float)tid * (1.0f / 64.0f), &s, &c);
    w64[tid] = make_float2(c, s);
  }
  __syncthreads();
  // phase 1: B[a*64+n1] = (sum_b ys[a+64b] W64^{n1 b}) * W4096^{n1 a}
#pragma unroll
  for (int l = 0; l < 4; ++l) {
    int o = tid + 1024 * l, a = o >> 6, n1 = o & 63;
    float ar = 0.f, ai = 0.f;
    for (int b = 0; b < 64; ++b) {
      float yr = ysr[a + (b << 6)], yi = ysi[a + (b << 6)];
      float2 w = w64[(n1 * b) & 63];
      ar += yr * w.x - yi * w.y;
      ai += yr * w.y + yi * w.x;
    }
    float s, c; __sincosf((float)((n1 * a) & 4095) * (TWO_PI / 4096.0f), &s, &c);
    br[o] = ar * c - ai * s;
    bi[o] = ar * s + ai * c;
  }
  __syncthreads();
  // phase 2: out[n1+64n2] += SCALE * Re( sum_a B[a*64+n1] W64^{n2 a} )
  float* orow = out + (size_t)t * 4096;
#pragma unroll
  for (int l = 0; l < 4; ++l) {
    int o = tid + 1024 * l, n1 = o & 63, n2 = o >> 6;
    float acc = 0.f;
    for (int a = 0; a < 64; ++a) {
      float brv = br[(a << 6) + n1], biv = bi[(a << 6) + n1];
      float2 w = w64[(n2 * a) & 63];
      acc += brv * w.x - biv * w.y;
    }
    orow[o] += acc * SCALE_A;
  }
}

// ---------------- Kernel D: base GEMM  out[t][f] = b[f] + sum_d x[t,d] W[f,d]
// fp32, LDS-tiled. TM=64 (t), TN=32 (f), TK=32. grid (128 f-tiles, 2 t-tiles), 256 thr.
__global__ __launch_bounds__(256) void gemm_base(const float* __restrict__ x,
                                                 const float* __restrict__ W,
                                                 const float* __restrict__ b,
                                                 float* __restrict__ out) {
  __shared__ float xs[64][33];
  __shared__ float ws[32][33];
  const int bf = blockIdx.x, bt = blockIdx.y;
  const int tid = threadIdx.x;
  const int tx = tid & 15;          // f: 16 groups of 2
  const int ty = tid >> 4;          // t: 16 groups of 4
  const int t0 = bt * 64, f0 = bf * 32;
  float acc[4][2] = {};
  for (int k0 = 0; k0 < 4096; k0 += 32) {
#pragma unroll
    for (int l = 0; l < 8; ++l) {
      int i = tid + 256 * l, r = i >> 5, c = i & 31;
      xs[r][c] = x[(size_t)(t0 + r) * 4096 + k0 + c];
    }
#pragma unroll
    for (int l = 0; l < 4; ++l) {
      int i = tid + 256 * l, r = i >> 5, c = i & 31;
      ws[r][c] = W[(size_t)(f0 + r) * 4096 + k0 + c];
    }
    __syncthreads();
#pragma unroll
    for (int kk = 0; kk < 32; ++kk) {
      float xv[4], wv[2];
#pragma unroll
      for (int i = 0; i < 4; ++i) xv[i] = xs[ty * 4 + i][kk];
#pragma unroll
      for (int j = 0; j < 2; ++j) wv[j] = ws[tx * 2 + j][kk];
#pragma unroll
      for (int i = 0; i < 4; ++i)
#pragma unroll
        for (int j = 0; j < 2; ++j) acc[i][j] = fmaf(xv[i], wv[j], acc[i][j]);
    }
    __syncthreads();
  }
#pragma unroll
  for (int i = 0; i < 4; ++i)
#pragma unroll
    for (int j = 0; j < 2; ++j) {
      int t = t0 + ty * 4 + i, f = f0 + tx * 2 + j;
      out[(size_t)t * 4096 + f] = acc[i][j] + b[f];
    }
}

extern "C" void kernel_launch(void* const* d_in, const int* in_sizes, int n_in,
                              void* d_out, int out_size, void* d_ws, size_t ws_size,
                              hipStream_t stream) {
  const float* x   = (const float*)d_in[0];
  const float* W   = (const float*)d_in[1];
  const float* b   = (const float*)d_in[2];
  const float* cre = (const float*)d_in[3];
  const float* cim = (const float*)d_in[4];
  const int* midx  = (const int*)d_in[5];
  const int K = in_sizes[3];
  float* out = (float*)d_out;

  char* ws = (char*)d_ws;
  float2* XT     = (float2*)(ws);                          // 4096*128*8  = 4 MB
  float2* Y      = (float2*)(ws + (size_t)(4 << 20));      // 128*4096*8  = 4 MB
  float4* bucket = (float4*)(ws + (size_t)(8 << 20));      // K*16 ~= 13.4 MB
  char* meta     = ws + (size_t)(22 << 20);
  int* count  = (int*)(meta);
  int* off    = (int*)(meta + 16384);
  int* cursor = (int*)(meta + 32768);

  hipMemsetAsync(meta, 0, 3 * 16384, stream);

  dft_rows_x<<<NROW, 1024, 0, stream>>>(x, XT);
  histo<<<(K + 255) / 256, 256, 0, stream>>>(midx, K, count);
  scan4096<<<1, 1024, 0, stream>>>(count, off);
  scatter_nz<<<(K + 255) / 256, 256, 0, stream>>>(midx, cre, cim, K, off, cursor, bucket);
  spmm_col<<<4096, 128, 0, stream>>>(bucket, off, count, XT, Y);
  gemm_base<<<dim3(128, 2), 256, 0, stream>>>(x, W, b, out);
  dft_rows_y<<<NROW, 1024, 0, stream>>>(Y, out);
}

// Round 2
// 333.115 us; speedup vs baseline: 1.4409x; 1.4409x over previous
//
#include <hip/hip_runtime.h>

// LFMA adapter: out = x@W_base^T + b + x @ (alpha * Re(ifft2(scatter(c, mask_idx))))
// Factored: never materialize Delta_W.
//   X[t,k1] = sum_m x[t,m] e^{+2pi i m k1/4096}          (kernel A, per-row DFT-4096)
//   Y[t,k2] = sum_{nz (k1,k2,c)} c * X[t,k1]             (bucketed sparse, kernels B1-B4)
//   out2[t,n] = SCALE * Re( sum_k2 Y[t,k2] e^{+2pi i n k2/4096} )   (kernel C)
// Base GEMM: bf16 MFMA, K-split partials + reduce (R2: replaces 237us fp32 gemm).

#define TWO_PI 6.28318530717958647692f
constexpr int NROW = 128;          // 2*64 rows of x
constexpr float SCALE_A = 16.0f / 16777216.0f;

typedef unsigned short ushort_t;
using short8 = __attribute__((ext_vector_type(8))) short;
using f32x4  = __attribute__((ext_vector_type(4))) float;

__device__ __forceinline__ ushort_t f2bf(float f) {
  unsigned u = __float_as_uint(f);
  u = (u + 0x7FFFu + ((u >> 16) & 1u)) >> 16;   // RNE
  return (ushort_t)u;
}

// ---------------- Kernel A: X^T[k][t] (transposed store for coalesced spmm gathers)
__global__ __launch_bounds__(1024) void dft_rows_x(const float* __restrict__ x,
                                                   float2* __restrict__ XT) {
  __shared__ float xs[4096];
  __shared__ float br[4096], bi[4096];
  __shared__ float2 w64[64];
  const int t = blockIdx.x, tid = threadIdx.x;
  const float* xrow = x + (size_t)t * 4096;
#pragma unroll
  for (int l = 0; l < 4; ++l) xs[tid + 1024 * l] = xrow[tid + 1024 * l];
  if (tid < 64) {
    float s, c; __sincosf(TWO_PI * (float)tid * (1.0f / 64.0f), &s, &c);
    w64[tid] = make_float2(c, s);          // W64^j = e^{+2pi i j/64}
  }
  __syncthreads();
#pragma unroll
  for (int l = 0; l < 4; ++l) {
    int o = tid + 1024 * l, m1 = o >> 6, k1 = o & 63;
    float ar = 0.f, ai = 0.f;
    for (int m2 = 0; m2 < 64; ++m2) {
      float xv = xs[m1 + (m2 << 6)];
      float2 w = w64[(m2 * k1) & 63];
      ar = fmaf(xv, w.x, ar); ai = fmaf(xv, w.y, ai);
    }
    float s, c; __sincosf((float)((m1 * k1) & 4095) * (TWO_PI / 4096.0f), &s, &c);
    br[o] = ar * c - ai * s;
    bi[o] = ar * s + ai * c;
  }
  __syncthreads();
#pragma unroll
  for (int l = 0; l < 4; ++l) {
    int o = tid + 1024 * l, k1 = o & 63, k2 = o >> 6;
    float xr = 0.f, xi = 0.f;
    for (int m1 = 0; m1 < 64; ++m1) {
      float brv = br[(m1 << 6) + k1], biv = bi[(m1 << 6) + k1];
      float2 w = w64[(m1 * k2) & 63];
      xr += brv * w.x - biv * w.y;
      xi += brv * w.y + biv * w.x;
    }
    XT[(size_t)o * NROW + t] = make_float2(xr, xi);
  }
}

// ---------------- B1: histogram of k2 = idx & 4095
__global__ void histo(const int* __restrict__ idx, int K, int* __restrict__ count) {
  int j = blockIdx.x * 256 + threadIdx.x;
  if (j < K) atomicAdd(&count[idx[j] & 4095], 1);
}

// ---------------- B2: exclusive scan over 4096 counts (single block)
__global__ __launch_bounds__(1024) void scan4096(const int* __restrict__ count,
                                                 int* __restrict__ off) {
  __shared__ int s[4096];
  int tid = threadIdx.x;
#pragma unroll
  for (int l = 0; l < 4; ++l) s[tid + 1024 * l] = count[tid + 1024 * l];
  __syncthreads();
  for (int d = 1; d < 4096; d <<= 1) {
    int v[4];
#pragma unroll
    for (int l = 0; l < 4; ++l) {
      int i = tid + 1024 * l;
      v[l] = s[i] + ((i >= d) ? s[i - d] : 0);
    }
    __syncthreads();
#pragma unroll
    for (int l = 0; l < 4; ++l) s[tid + 1024 * l] = v[l];
    __syncthreads();
  }
#pragma unroll
  for (int l = 0; l < 4; ++l) {
    int i = tid + 1024 * l;
    off[i] = s[i] - count[i];
  }
}

// ---------------- B3: scatter nonzeros into column buckets
__global__ void scatter_nz(const int* __restrict__ idx, const float* __restrict__ cre,
                           const float* __restrict__ cim, int K,
                           const int* __restrict__ off, int* __restrict__ cursor,
                           float4* __restrict__ bucket) {
  int j = blockIdx.x * 256 + threadIdx.x;
  if (j < K) {
    int p = idx[j];
    int k2 = p & 4095, k1 = p >> 12;
    int pos = off[k2] + atomicAdd(&cursor[k2], 1);
    bucket[pos] = make_float4(__int_as_float(k1), cre[j], cim[j], 0.f);
  }
}

// ---------------- B4: per-column sparse accumulate  Y[t][k2] = sum c * X[t,k1]
__global__ __launch_bounds__(128) void spmm_col(const float4* __restrict__ bucket,
                                                const int* __restrict__ off,
                                                const int* __restrict__ count,
                                                const float2* __restrict__ XT,
                                                float2* __restrict__ Y) {
  int k2 = blockIdx.x;
  int t = threadIdx.x;
  int s = off[k2], n = count[k2];
  float ar = 0.f, ai = 0.f;
  for (int j = 0; j < n; ++j) {
    float4 e = bucket[s + j];
    int k1 = __float_as_int(e.x);
    float2 xv = XT[(size_t)k1 * NROW + t];
    ar += e.y * xv.x - e.z * xv.y;
    ai += e.y * xv.y + e.z * xv.x;
  }
  Y[(size_t)t * 4096 + k2] = make_float2(ar, ai);
}

// ---------------- Kernel C: out[t][n] += SCALE * Re(DFT-4096 of Y row)
__global__ __launch_bounds__(1024) void dft_rows_y(const float2* __restrict__ Y,
                                                   float* __restrict__ out) {
  __shared__ float ysr[4096], ysi[4096];
  __shared__ float br[4096], bi[4096];
  __shared__ float2 w64[64];
  const int t = blockIdx.x, tid = threadIdx.x;
  const float2* yrow = Y + (size_t)t * 4096;
#pragma unroll
  for (int l = 0; l < 4; ++l) {
    float2 v = yrow[tid + 1024 * l];
    ysr[tid + 1024 * l] = v.x; ysi[tid + 1024 * l] = v.y;
  }
  if (tid < 64) {
    float s, c; __sincosf(TWO_PI * (float)tid * (1.0f / 64.0f), &s, &c);
    w64[tid] = make_float2(c, s);
  }
  __syncthreads();
#pragma unroll
  for (int l = 0; l < 4; ++l) {
    int o = tid + 1024 * l, a = o >> 6, n1 = o & 63;
    float ar = 0.f, ai = 0.f;
    for (int b = 0; b < 64; ++b) {
      float yr = ysr[a + (b << 6)], yi = ysi[a + (b << 6)];
      float2 w = w64[(n1 * b) & 63];
      ar += yr * w.x - yi * w.y;
      ai += yr * w.y + yi * w.x;
    }
    float s, c; __sincosf((float)((n1 * a) & 4095) * (TWO_PI / 4096.0f), &s, &c);
    br[o] = ar * c - ai * s;
    bi[o] = ar * s + ai * c;
  }
  __syncthreads();
  float* orow = out + (size_t)t * 4096;
#pragma unroll
  for (int l = 0; l < 4; ++l) {
    int o = tid + 1024 * l, n1 = o & 63, n2 = o >> 6;
    float acc = 0.f;
    for (int a = 0; a < 64; ++a) {
      float brv = br[(a << 6) + n1], biv = bi[(a << 6) + n1];
      float2 w = w64[(n2 * a) & 63];
      acc += brv * w.x - biv * w.y;
    }
    orow[o] += acc * SCALE_A;
  }
}

// ---------------- x -> bf16 pre-convert (so per-block re-reads are cheap L2/L3 bf16)
__global__ __launch_bounds__(256) void xcvt(const float* __restrict__ x,
                                            ushort_t* __restrict__ xbf) {
  size_t e = ((size_t)blockIdx.x * 256 + threadIdx.x) * 4;
  float4 v = *(const float4*)(x + e);
  unsigned lo = (unsigned)f2bf(v.x) | ((unsigned)f2bf(v.y) << 16);
  unsigned hi = (unsigned)f2bf(v.z) | ((unsigned)f2bf(v.w) << 16);
  *(uint2*)(xbf + e) = make_uint2(lo, hi);
}

// ---------------- base GEMM partials: part[kc][t][f] = sum_{k in chunk} x[t,k] W[f,k]
// grid (64 N-tiles, 4 K-chunks), 256 threads (4 waves). Tile 128(t) x 64(f) x BK=64.
__global__ __launch_bounds__(256) void gemm_mfma_partial(const ushort_t* __restrict__ xbf,
                                                         const float* __restrict__ W,
                                                         float* __restrict__ part) {
  __shared__ ushort_t xs[128 * 64];   // 16 KB, XOR-swizzled 16B slots
  __shared__ ushort_t wsl[64 * 64];   // 8 KB
  const int f0 = blockIdx.x * 64;
  const int kc = blockIdx.y;
  const int tid = threadIdx.x;
  const int w = tid >> 6, lane = tid & 63;

  f32x4 acc[2][4];
#pragma unroll
  for (int i = 0; i < 2; ++i)
#pragma unroll
    for (int j = 0; j < 4; ++j) acc[i][j] = (f32x4){0.f, 0.f, 0.f, 0.f};

  const int kbeg = kc * 1024;
  for (int k0 = kbeg; k0 < kbeg + 1024; k0 += 64) {
    // stage x tile [128][64] bf16 (already bf16 in xbf): 1024 16B slots
#pragma unroll
    for (int l = 0; l < 4; ++l) {
      int s = tid + 256 * l, r = s >> 3, ks = s & 7;
      uint4 v = *(const uint4*)(xbf + (size_t)r * 4096 + k0 + ks * 8);
      *(uint4*)(&xs[r * 64 + ((ks ^ (r & 7)) << 3)]) = v;
    }
    // stage W tile [64][64]: load fp32, cvt to bf16: 512 slots
#pragma unroll
    for (int l = 0; l < 2; ++l) {
      int s = tid + 256 * l, r = s >> 3, ks = s & 7;
      const float* wp = W + (size_t)(f0 + r) * 4096 + k0 + ks * 8;
      float4 a = *(const float4*)(wp);
      float4 b = *(const float4*)(wp + 4);
      uint4 pk;
      pk.x = (unsigned)f2bf(a.x) | ((unsigned)f2bf(a.y) << 16);
      pk.y = (unsigned)f2bf(a.z) | ((unsigned)f2bf(a.w) << 16);
      pk.z = (unsigned)f2bf(b.x) | ((unsigned)f2bf(b.y) << 16);
      pk.w = (unsigned)f2bf(b.z) | ((unsigned)f2bf(b.w) << 16);
      *(uint4*)(&wsl[r * 64 + ((ks ^ (r & 7)) << 3)]) = pk;
    }
    __syncthreads();
#pragma unroll
    for (int kk = 0; kk < 2; ++kk) {
      int ksA = kk * 4 + (lane >> 4);
      short8 af[2], bfr[4];
#pragma unroll
      for (int mf = 0; mf < 2; ++mf) {
        int ra = w * 32 + mf * 16 + (lane & 15);
        af[mf] = *(const short8*)(&xs[ra * 64 + ((ksA ^ (ra & 7)) << 3)]);
      }
#pragma unroll
      for (int nf = 0; nf < 4; ++nf) {
        int rb = nf * 16 + (lane & 15);
        bfr[nf] = *(const short8*)(&wsl[rb * 64 + ((ksA ^ (rb & 7)) << 3)]);
      }
#pragma unroll
      for (int mf = 0; mf < 2; ++mf)
#pragma unroll
        for (int nf = 0; nf < 4; ++nf)
          acc[mf][nf] = __builtin_amdgcn_mfma_f32_16x16x32_bf16(af[mf], bfr[nf], acc[mf][nf], 0, 0, 0);
    }
    __syncthreads();
  }
  // epilogue: C/D layout col=lane&15, row=(lane>>4)*4+reg
  float* pb = part + ((size_t)kc << 19);
#pragma unroll
  for (int mf = 0; mf < 2; ++mf)
#pragma unroll
    for (int nf = 0; nf < 4; ++nf)
#pragma unroll
      for (int reg = 0; reg < 4; ++reg) {
        int row = w * 32 + mf * 16 + (lane >> 4) * 4 + reg;
        int col = f0 + nf * 16 + (lane & 15);
        pb[(size_t)row * 4096 + col] = acc[mf][nf][reg];
      }
}

// ---------------- reduce partials + bias -> out
__global__ __launch_bounds__(256) void reduce_bias(const float* __restrict__ part,
                                                   const float* __restrict__ b,
                                                   float* __restrict__ out) {
  size_t e = ((size_t)blockIdx.x * 256 + threadIdx.x) * 4;
  int f = (int)(e & 4095);
  float4 v0 = *(const float4*)(part + e);
  float4 v1 = *(const float4*)(part + e + (1ull << 19));
  float4 v2 = *(const float4*)(part + e + (2ull << 19));
  float4 v3 = *(const float4*)(part + e + (3ull << 19));
  float4 bb = *(const float4*)(b + f);
  float4 o;
  o.x = bb.x + v0.x + v1.x + v2.x + v3.x;
  o.y = bb.y + v0.y + v1.y + v2.y + v3.y;
  o.z = bb.z + v0.z + v1.z + v2.z + v3.z;
  o.w = bb.w + v0.w + v1.w + v2.w + v3.w;
  *(float4*)(out + e) = o;
}

extern "C" void kernel_launch(void* const* d_in, const int* in_sizes, int n_in,
                              void* d_out, int out_size, void* d_ws, size_t ws_size,
                              hipStream_t stream) {
  const float* x   = (const float*)d_in[0];
  const float* W   = (const float*)d_in[1];
  const float* b   = (const float*)d_in[2];
  const float* cre = (const float*)d_in[3];
  const float* cim = (const float*)d_in[4];
  const int* midx  = (const int*)d_in[5];
  const int K = in_sizes[3];
  float* out = (float*)d_out;

  char* ws = (char*)d_ws;
  float2* XT     = (float2*)(ws);                          // 4096*128*8  = 4 MB
  float2* Y      = (float2*)(ws + (size_t)(4 << 20));      // 128*4096*8  = 4 MB
  float4* bucket = (float4*)(ws + (size_t)(8 << 20));      // K*16 ~= 13.4 MB
  float*  part   = (float*)(ws + (size_t)(8 << 20));       // 8 MB, ALIASES bucket:
                                                           // bucket fully consumed by
                                                           // spmm_col before gemm writes
  char* meta     = ws + (size_t)(22 << 20);
  int* count  = (int*)(meta);
  int* off    = (int*)(meta + 16384);
  int* cursor = (int*)(meta + 32768);
  ushort_t* xbf = (ushort_t*)(ws + (size_t)(22 << 20) + 65536);  // 1 MB

  hipMemsetAsync(meta, 0, 3 * 16384, stream);

  xcvt<<<512, 256, 0, stream>>>(x, xbf);
  dft_rows_x<<<NROW, 1024, 0, stream>>>(x, XT);
  histo<<<(K + 255) / 256, 256, 0, stream>>>(midx, K, count);
  scan4096<<<1, 1024, 0, stream>>>(count, off);
  scatter_nz<<<(K + 255) / 256, 256, 0, stream>>>(midx, cre, cim, K, off, cursor, bucket);
  spmm_col<<<4096, 128, 0, stream>>>(bucket, off, count, XT, Y);
  gemm_mfma_partial<<<dim3(64, 4), 256, 0, stream>>>(xbf, W, part);
  reduce_bias<<<512, 256, 0, stream>>>(part, b, out);
  dft_rows_y<<<NROW, 1024, 0, stream>>>(Y, out);
}

// Round 3
// 265.691 us; speedup vs baseline: 1.8066x; 1.2538x over previous
//
#include <hip/hip_runtime.h>

// LFMA adapter: out = x@W_base^T + b + x @ (alpha * Re(ifft2(scatter(c, mask_idx))))
// Factored: never materialize Delta_W.
//   X[t,k1] = sum_m x[t,m] e^{+2pi i m k1/4096}   (dft_rows_x; Hermitian: store k<=2048, bf16)
//   Y[t,k2] = sum_{nz (k1,k2,c)} c * X[t,k1]      (bucketed sparse, readlane-broadcast spmm)
//   out2[t,n] = SCALE * Re( sum_k2 Y[t,k2] e^{+2pi i n k2/4096} )   (dft_rows_y)
// Base GEMM: bf16 MFMA, K-split partials + reduce.

#define TWO_PI 6.28318530717958647692f
constexpr int NROW = 128;
constexpr float SCALE_A = 16.0f / 16777216.0f;

typedef unsigned short ushort_t;
using short8 = __attribute__((ext_vector_type(8))) short;
using f32x4  = __attribute__((ext_vector_type(4))) float;

__device__ __forceinline__ ushort_t f2bf(float f) {
  unsigned u = __float_as_uint(f);
  u = (u + 0x7FFFu + ((u >> 16) & 1u)) >> 16;   // RNE
  return (ushort_t)u;
}

// ---------------- Kernel A: XTb[k][t] packed bf16 complex, k in [0,2048] only (Hermitian)
// grid (128 rows, 2 phase2-halves), 1024 thr.
__global__ __launch_bounds__(1024) void dft_rows_x(const float* __restrict__ x,
                                                   unsigned* __restrict__ XTb) {
  __shared__ float xs[4096];
  __shared__ float br[4096], bi[4096];
  __shared__ float2 w64[64];
  const int t = blockIdx.x, qi = blockIdx.y, tid = threadIdx.x;
  const float* xrow = x + (size_t)t * 4096;
#pragma unroll
  for (int l = 0; l < 4; ++l) xs[tid + 1024 * l] = xrow[tid + 1024 * l];
  if (tid < 64) {
    float s, c; __sincosf(TWO_PI * (float)tid * (1.0f / 64.0f), &s, &c);
    w64[tid] = make_float2(c, s);          // W64^j = e^{+2pi i j/64}
  }
  __syncthreads();
  // phase 1 (full, duplicated across qi): B[m1*64+k1]
#pragma unroll
  for (int l = 0; l < 4; ++l) {
    int o = tid + 1024 * l, m1 = o >> 6, k1 = o & 63;
    float ar = 0.f, ai = 0.f;
    for (int m2 = 0; m2 < 64; ++m2) {
      float xv = xs[m1 + (m2 << 6)];
      float2 w = w64[(m2 * k1) & 63];
      ar = fmaf(xv, w.x, ar); ai = fmaf(xv, w.y, ai);
    }
    float s, c; __sincosf((float)(m1 * k1) * (TWO_PI / 4096.0f), &s, &c);
    br[o] = ar * c - ai * s;
    bi[o] = ar * s + ai * c;
  }
  __syncthreads();
  // phase 2: k = k1 + 64*k2, only k <= 2048. qi=0: k2 0..15, qi=1: k2 16..32.
  const int k2lo = qi * 16, k2hi = k2lo + 16 + qi;
  const int k1 = tid & 63;
  for (int k2 = k2lo + (tid >> 6); k2 < k2hi; k2 += 16) {
    int k = k1 + (k2 << 6);
    if (k <= 2048) {
      float xr = 0.f, xi = 0.f;
      for (int m1 = 0; m1 < 64; ++m1) {
        float brv = br[(m1 << 6) + k1], biv = bi[(m1 << 6) + k1];
        float2 w = w64[(m1 * k2) & 63];
        xr += brv * w.x - biv * w.y;
        xi += brv * w.y + biv * w.x;
      }
      XTb[(size_t)k * NROW + t] = (unsigned)f2bf(xr) | ((unsigned)f2bf(xi) << 16);
    }
  }
}

// ---------------- B1: histogram of k2 = idx & 4095
__global__ void histo(const int* __restrict__ idx, int K, int* __restrict__ count) {
  int j = blockIdx.x * 256 + threadIdx.x;
  if (j < K) atomicAdd(&count[idx[j] & 4095], 1);
}

// ---------------- B2: exclusive scan over 4096 counts (single block)
__global__ __launch_bounds__(1024) void scan4096(const int* __restrict__ count,
                                                 int* __restrict__ off) {
  __shared__ int s[4096];
  int tid = threadIdx.x;
#pragma unroll
  for (int l = 0; l < 4; ++l) s[tid + 1024 * l] = count[tid + 1024 * l];
  __syncthreads();
  for (int d = 1; d < 4096; d <<= 1) {
    int v[4];
#pragma unroll
    for (int l = 0; l < 4; ++l) {
      int i = tid + 1024 * l;
      v[l] = s[i] + ((i >= d) ? s[i - d] : 0);
    }
    __syncthreads();
#pragma unroll
    for (int l = 0; l < 4; ++l) s[tid + 1024 * l] = v[l];
    __syncthreads();
  }
#pragma unroll
  for (int l = 0; l < 4; ++l) {
    int i = tid + 1024 * l;
    off[i] = s[i] - count[i];
  }
}

// ---------------- B3: scatter nonzeros into column buckets
__global__ void scatter_nz(const int* __restrict__ idx, const float* __restrict__ cre,
                           const float* __restrict__ cim, int K,
                           const int* __restrict__ off, int* __restrict__ cursor,
                           float4* __restrict__ bucket) {
  int j = blockIdx.x * 256 + threadIdx.x;
  if (j < K) {
    int p = idx[j];
    int k2 = p & 4095, k1 = p >> 12;
    int pos = off[k2] + atomicAdd(&cursor[k2], 1);
    bucket[pos] = make_float4(__int_as_float(k1), cre[j], cim[j], 0.f);
  }
}

// ---------------- B4: Y[t][k2] = sum c * X[t,k1], 1 wave per column, 2 t per lane.
// Bucket entries chunk-loaded (1/lane) then readlane-broadcast -> SGPR-base gathers.
__global__ __launch_bounds__(256) void spmm_col(const float4* __restrict__ bucket,
                                                const int* __restrict__ off,
                                                const int* __restrict__ count,
                                                const unsigned* __restrict__ XTb,
                                                float2* __restrict__ Y) {
  const int lane = threadIdx.x & 63;
  const int k2 = blockIdx.x * 4 + (threadIdx.x >> 6);
  const int s = off[k2], n = count[k2];
  float ar0 = 0.f, ai0 = 0.f, ar1 = 0.f, ai1 = 0.f;
  for (int c = 0; c < n; c += 64) {
    int idx = c + lane;
    float4 ec = (idx < n) ? bucket[s + idx] : make_float4(0.f, 0.f, 0.f, 0.f);
#pragma unroll
    for (int j = 0; j < 64; ++j) {
      int k1  = __builtin_amdgcn_readlane(__float_as_int(ec.x), j);
      int crb = __builtin_amdgcn_readlane(__float_as_int(ec.y), j);
      int cib = __builtin_amdgcn_readlane(__float_as_int(ec.z), j);
      int negm = (k1 > 2048) ? (int)0x80000000 : 0;        // scalar
      int r = (k1 > 2048) ? 4096 - k1 : k1;                // conj row
      float cr  = __int_as_float(crb);
      float ci  = __int_as_float(cib);
      float crs = __int_as_float(crb ^ negm);
      float cis = __int_as_float(cib ^ negm);
      uint2 xv = *(const uint2*)(XTb + (size_t)r * NROW + 2 * lane);
      float xr0 = __int_as_float(xv.x << 16);
      float xi0 = __int_as_float(xv.x & 0xffff0000u);
      float xr1 = __int_as_float(xv.y << 16);
      float xi1 = __int_as_float(xv.y & 0xffff0000u);
      // c * (xr + i*sgn*xi):  ar += cr*xr - cis*xi ; ai += crs*xi + ci*xr
      ar0 = fmaf(cr, xr0, ar0);  ar0 = fmaf(-cis, xi0, ar0);
      ai0 = fmaf(crs, xi0, ai0); ai0 = fmaf(ci, xr0, ai0);
      ar1 = fmaf(cr, xr1, ar1);  ar1 = fmaf(-cis, xi1, ar1);
      ai1 = fmaf(crs, xi1, ai1); ai1 = fmaf(ci, xr1, ai1);
    }
  }
  Y[(size_t)(2 * lane) * 4096 + k2]     = make_float2(ar0, ai0);
  Y[(size_t)(2 * lane + 1) * 4096 + k2] = make_float2(ar1, ai1);
}

// ---------------- Kernel C: out[t][n] += SCALE * Re(DFT-4096 of Y row). grid (128,2).
__global__ __launch_bounds__(1024) void dft_rows_y(const float2* __restrict__ Y,
                                                   float* __restrict__ out) {
  __shared__ float ysr[4096], ysi[4096];
  __shared__ float br[4096], bi[4096];
  __shared__ float2 w64[64];
  const int t = blockIdx.x, qi = blockIdx.y, tid = threadIdx.x;
  const float2* yrow = Y + (size_t)t * 4096;
#pragma unroll
  for (int l = 0; l < 4; ++l) {
    float2 v = yrow[tid + 1024 * l];
    ysr[tid + 1024 * l] = v.x; ysi[tid + 1024 * l] = v.y;
  }
  if (tid < 64) {
    float s, c; __sincosf(TWO_PI * (float)tid * (1.0f / 64.0f), &s, &c);
    w64[tid] = make_float2(c, s);
  }
  __syncthreads();
  // phase 1 (full, duplicated across qi)
#pragma unroll
  for (int l = 0; l < 4; ++l) {
    int o = tid + 1024 * l, a = o >> 6, n1 = o & 63;
    float ar = 0.f, ai = 0.f;
    for (int b = 0; b < 64; ++b) {
      float yr = ysr[a + (b << 6)], yi = ysi[a + (b << 6)];
      float2 w = w64[(n1 * b) & 63];
      ar += yr * w.x - yi * w.y;
      ai += yr * w.y + yi * w.x;
    }
    float s, c; __sincosf((float)(n1 * a) * (TWO_PI / 4096.0f), &s, &c);
    br[o] = ar * c - ai * s;
    bi[o] = ar * s + ai * c;
  }
  __syncthreads();
  // phase 2: n2 in [qi*32, qi*32+32), 16 waves -> 2 n2 per wave
  float* orow = out + (size_t)t * 4096;
  const int n1 = tid & 63;
  for (int n2 = qi * 32 + (tid >> 6); n2 < qi * 32 + 32; n2 += 16) {
    float acc = 0.f;
    for (int a = 0; a < 64; ++a) {
      float brv = br[(a << 6) + n1], biv = bi[(a << 6) + n1];
      float2 w = w64[(n2 * a) & 63];
      acc += brv * w.x - biv * w.y;
    }
    orow[n1 + (n2 << 6)] += acc * SCALE_A;
  }
}

// ---------------- x -> bf16 pre-convert
__global__ __launch_bounds__(256) void xcvt(const float* __restrict__ x,
                                            ushort_t* __restrict__ xbf) {
  size_t e = ((size_t)blockIdx.x * 256 + threadIdx.x) * 4;
  float4 v = *(const float4*)(x + e);
  unsigned lo = (unsigned)f2bf(v.x) | ((unsigned)f2bf(v.y) << 16);
  unsigned hi = (unsigned)f2bf(v.z) | ((unsigned)f2bf(v.w) << 16);
  *(uint2*)(xbf + e) = make_uint2(lo, hi);
}

// ---------------- base GEMM partials: part[kc][t][f], tile 128(t) x 64(f) x 64(k)
__global__ __launch_bounds__(256) void gemm_mfma_partial(const ushort_t* __restrict__ xbf,
                                                         const float* __restrict__ W,
                                                         float* __restrict__ part) {
  __shared__ ushort_t xs[128 * 64];
  __shared__ ushort_t wsl[64 * 64];
  const int f0 = blockIdx.x * 64;
  const int kc = blockIdx.y;
  const int tid = threadIdx.x;
  const int w = tid >> 6, lane = tid & 63;

  f32x4 acc[2][4];
#pragma unroll
  for (int i = 0; i < 2; ++i)
#pragma unroll
    for (int j = 0; j < 4; ++j) acc[i][j] = (f32x4){0.f, 0.f, 0.f, 0.f};

  const int kbeg = kc * 1024;
  for (int k0 = kbeg; k0 < kbeg + 1024; k0 += 64) {
#pragma unroll
    for (int l = 0; l < 4; ++l) {
      int s = tid + 256 * l, r = s >> 3, ks = s & 7;
      uint4 v = *(const uint4*)(xbf + (size_t)r * 4096 + k0 + ks * 8);
      *(uint4*)(&xs[r * 64 + ((ks ^ (r & 7)) << 3)]) = v;
    }
#pragma unroll
    for (int l = 0; l < 2; ++l) {
      int s = tid + 256 * l, r = s >> 3, ks = s & 7;
      const float* wp = W + (size_t)(f0 + r) * 4096 + k0 + ks * 8;
      float4 a = *(const float4*)(wp);
      float4 b = *(const float4*)(wp + 4);
      uint4 pk;
      pk.x = (unsigned)f2bf(a.x) | ((unsigned)f2bf(a.y) << 16);
      pk.y = (unsigned)f2bf(a.z) | ((unsigned)f2bf(a.w) << 16);
      pk.z = (unsigned)f2bf(b.x) | ((unsigned)f2bf(b.y) << 16);
      pk.w = (unsigned)f2bf(b.z) | ((unsigned)f2bf(b.w) << 16);
      *(uint4*)(&wsl[r * 64 + ((ks ^ (r & 7)) << 3)]) = pk;
    }
    __syncthreads();
#pragma unroll
    for (int kk = 0; kk < 2; ++kk) {
      int ksA = kk * 4 + (lane >> 4);
      short8 af[2], bfr[4];
#pragma unroll
      for (int mf = 0; mf < 2; ++mf) {
        int ra = w * 32 + mf * 16 + (lane & 15);
        af[mf] = *(const short8*)(&xs[ra * 64 + ((ksA ^ (ra & 7)) << 3)]);
      }
#pragma unroll
      for (int nf = 0; nf < 4; ++nf) {
        int rb = nf * 16 + (lane & 15);
        bfr[nf] = *(const short8*)(&wsl[rb * 64 + ((ksA ^ (rb & 7)) << 3)]);
      }
#pragma unroll
      for (int mf = 0; mf < 2; ++mf)
#pragma unroll
        for (int nf = 0; nf < 4; ++nf)
          acc[mf][nf] = __builtin_amdgcn_mfma_f32_16x16x32_bf16(af[mf], bfr[nf], acc[mf][nf], 0, 0, 0);
    }
    __syncthreads();
  }
  float* pb = part + ((size_t)kc << 19);
#pragma unroll
  for (int mf = 0; mf < 2; ++mf)
#pragma unroll
    for (int nf = 0; nf < 4; ++nf)
#pragma unroll
      for (int reg = 0; reg < 4; ++reg) {
        int row = w * 32 + mf * 16 + (lane >> 4) * 4 + reg;
        int col = f0 + nf * 16 + (lane & 15);
        pb[(size_t)row * 4096 + col] = acc[mf][nf][reg];
      }
}

// ---------------- reduce partials + bias -> out
__global__ __launch_bounds__(256) void reduce_bias(const float* __restrict__ part,
                                                   const float* __restrict__ b,
                                                   float* __restrict__ out) {
  size_t e = ((size_t)blockIdx.x * 256 + threadIdx.x) * 4;
  int f = (int)(e & 4095);
  float4 v0 = *(const float4*)(part + e);
  float4 v1 = *(const float4*)(part + e + (1ull << 19));
  float4 v2 = *(const float4*)(part + e + (2ull << 19));
  float4 v3 = *(const float4*)(part + e + (3ull << 19));
  float4 bb = *(const float4*)(b + f);
  float4 o;
  o.x = bb.x + v0.x + v1.x + v2.x + v3.x;
  o.y = bb.y + v0.y + v1.y + v2.y + v3.y;
  o.z = bb.z + v0.z + v1.z + v2.z + v3.z;
  o.w = bb.w + v0.w + v1.w + v2.w + v3.w;
  *(float4*)(out + e) = o;
}

extern "C" void kernel_launch(void* const* d_in, const int* in_sizes, int n_in,
                              void* d_out, int out_size, void* d_ws, size_t ws_size,
                              hipStream_t stream) {
  const float* x   = (const float*)d_in[0];
  const float* W   = (const float*)d_in[1];
  const float* b   = (const float*)d_in[2];
  const float* cre = (const float*)d_in[3];
  const float* cim = (const float*)d_in[4];
  const int* midx  = (const int*)d_in[5];
  const int K = in_sizes[3];
  float* out = (float*)d_out;

  char* ws = (char*)d_ws;
  unsigned* XTb  = (unsigned*)(ws);                        // 2049*128*4 ~= 1.05 MB
  float2* Y      = (float2*)(ws + (size_t)(2 << 20));      // 4 MB
  float4* bucket = (float4*)(ws + (size_t)(6 << 20));      // K*16 ~= 13.4 MB -> ends 19.42M
  float*  part   = (float*)(ws + (size_t)(6 << 20));       // 8 MB, ALIASES bucket (bucket
                                                           // consumed by spmm_col first)
  char* meta     = ws + (size_t)(20 << 20);
  int* count  = (int*)(meta);
  int* off    = (int*)(meta + 16384);
  int* cursor = (int*)(meta + 32768);
  ushort_t* xbf = (ushort_t*)(ws + (size_t)(20 << 20) + 65536);  // 1 MB

  hipMemsetAsync(meta, 0, 3 * 16384, stream);

  xcvt<<<512, 256, 0, stream>>>(x, xbf);
  dft_rows_x<<<dim3(NROW, 2), 1024, 0, stream>>>(x, XTb);
  histo<<<(K + 255) / 256, 256, 0, stream>>>(midx, K, count);
  scan4096<<<1, 1024, 0, stream>>>(count, off);
  scatter_nz<<<(K + 255) / 256, 256, 0, stream>>>(midx, cre, cim, K, off, cursor, bucket);
  spmm_col<<<1024, 256, 0, stream>>>(bucket, off, count, XTb, Y);
  gemm_mfma_partial<<<dim3(64, 4), 256, 0, stream>>>(xbf, W, part);
  reduce_bias<<<512, 256, 0, stream>>>(part, b, out);
  dft_rows_y<<<dim3(NROW, 2), 1024, 0, stream>>>(Y, out);
}

// Round 4
// 168.860 us; speedup vs baseline: 2.8426x; 1.5734x over previous
//
#include <hip/hip_runtime.h>

// LFMA adapter: out = x@W_base^T + b + x @ (alpha * Re(ifft2(scatter(c, mask_idx))))
// Factored: never materialize Delta_W.
//   X[t,k1] = sum_m x[t,m] e^{+2pi i m k1/4096}   (dft_rows_x; Hermitian: store k<=2048, bf16)
//   Y[t,k2] = sum_{nz (k1,k2,c)} c * X[t,k1]      (bucketed sparse, readlane-broadcast spmm)
//   out2[t,n] = SCALE * Re( sum_k2 Y[t,k2] e^{+2pi i n k2/4096} )   (dft_rows_y)
// Bucketing: deterministic two-pass (LDS histograms + column scan), no returning
// global atomics (R4: replaces 62us atomic-cursor scatter + 10us histo).
// Base GEMM: bf16 MFMA, K-split partials + reduce.

#define TWO_PI 6.28318530717958647692f
constexpr int NROW = 128;
constexpr float SCALE_A = 16.0f / 16777216.0f;
constexpr int NCHUNK = 256;

typedef unsigned short ushort_t;
using short8 = __attribute__((ext_vector_type(8))) short;
using f32x4  = __attribute__((ext_vector_type(4))) float;

__device__ __forceinline__ ushort_t f2bf(float f) {
  unsigned u = __float_as_uint(f);
  u = (u + 0x7FFFu + ((u >> 16) & 1u)) >> 16;   // RNE
  return (ushort_t)u;
}

// ---------------- Kernel A: XTb[k][t] packed bf16 complex, k in [0,2048] only (Hermitian)
__global__ __launch_bounds__(1024) void dft_rows_x(const float* __restrict__ x,
                                                   unsigned* __restrict__ XTb) {
  __shared__ float xs[4096];
  __shared__ float br[4096], bi[4096];
  __shared__ float2 w64[64];
  const int t = blockIdx.x, qi = blockIdx.y, tid = threadIdx.x;
  const float* xrow = x + (size_t)t * 4096;
#pragma unroll
  for (int l = 0; l < 4; ++l) xs[tid + 1024 * l] = xrow[tid + 1024 * l];
  if (tid < 64) {
    float s, c; __sincosf(TWO_PI * (float)tid * (1.0f / 64.0f), &s, &c);
    w64[tid] = make_float2(c, s);          // W64^j = e^{+2pi i j/64}
  }
  __syncthreads();
#pragma unroll
  for (int l = 0; l < 4; ++l) {
    int o = tid + 1024 * l, m1 = o >> 6, k1 = o & 63;
    float ar = 0.f, ai = 0.f;
    for (int m2 = 0; m2 < 64; ++m2) {
      float xv = xs[m1 + (m2 << 6)];
      float2 w = w64[(m2 * k1) & 63];
      ar = fmaf(xv, w.x, ar); ai = fmaf(xv, w.y, ai);
    }
    float s, c; __sincosf((float)(m1 * k1) * (TWO_PI / 4096.0f), &s, &c);
    br[o] = ar * c - ai * s;
    bi[o] = ar * s + ai * c;
  }
  __syncthreads();
  const int k2lo = qi * 16, k2hi = k2lo + 16 + qi;
  const int k1 = tid & 63;
  for (int k2 = k2lo + (tid >> 6); k2 < k2hi; k2 += 16) {
    int k = k1 + (k2 << 6);
    if (k <= 2048) {
      float xr = 0.f, xi = 0.f;
      for (int m1 = 0; m1 < 64; ++m1) {
        float brv = br[(m1 << 6) + k1], biv = bi[(m1 << 6) + k1];
        float2 w = w64[(m1 * k2) & 63];
        xr += brv * w.x - biv * w.y;
        xi += brv * w.y + biv * w.x;
      }
      XTb[(size_t)k * NROW + t] = (unsigned)f2bf(xr) | ((unsigned)f2bf(xi) << 16);
    }
  }
}

// ---------------- S1: per-chunk LDS histogram of k2
__global__ __launch_bounds__(1024) void count_chunks(const int* __restrict__ idx, int K,
                                                     int chunk, int* __restrict__ cnt) {
  __shared__ int h[4096];
  const int c = blockIdx.x, tid = threadIdx.x;
#pragma unroll
  for (int l = 0; l < 4; ++l) h[tid + 1024 * l] = 0;
  __syncthreads();
  const int j0 = c * chunk, j1 = min(j0 + chunk, K);
  for (int j = j0 + tid; j < j1; j += 1024) atomicAdd(&h[idx[j] & 4095], 1);
  __syncthreads();
#pragma unroll
  for (int l = 0; l < 4; ++l) cnt[(size_t)c * 4096 + tid + 1024 * l] = h[tid + 1024 * l];
}

// ---------------- S2: per-column exclusive scan over chunks (in place) + totals
__global__ __launch_bounds__(256) void colscan(int* __restrict__ cnt, int* __restrict__ tot) {
  const int k2 = blockIdx.x * 256 + threadIdx.x;
  int run = 0;
  for (int c8 = 0; c8 < NCHUNK; c8 += 8) {
    int v[8];
#pragma unroll
    for (int i = 0; i < 8; ++i) v[i] = cnt[(size_t)(c8 + i) * 4096 + k2];
#pragma unroll
    for (int i = 0; i < 8; ++i) {
      cnt[(size_t)(c8 + i) * 4096 + k2] = run;
      run += v[i];
    }
  }
  tot[k2] = run;
}

// ---------------- B2: exclusive scan over 4096 totals (single block)
__global__ __launch_bounds__(1024) void scan4096(const int* __restrict__ count,
                                                 int* __restrict__ off) {
  __shared__ int s[4096];
  int tid = threadIdx.x;
#pragma unroll
  for (int l = 0; l < 4; ++l) s[tid + 1024 * l] = count[tid + 1024 * l];
  __syncthreads();
  for (int d = 1; d < 4096; d <<= 1) {
    int v[4];
#pragma unroll
    for (int l = 0; l < 4; ++l) {
      int i = tid + 1024 * l;
      v[l] = s[i] + ((i >= d) ? s[i - d] : 0);
    }
    __syncthreads();
#pragma unroll
    for (int l = 0; l < 4; ++l) s[tid + 1024 * l] = v[l];
    __syncthreads();
  }
#pragma unroll
  for (int l = 0; l < 4; ++l) {
    int i = tid + 1024 * l;
    off[i] = s[i] - count[i];
  }
}

// ---------------- S3: scatter with LDS-rank (no returning global atomics)
// entry: word0 = k1 | (bf16(cre)<<16), word1 = bf16(cim)<<16
__global__ __launch_bounds__(1024) void scatter2(const int* __restrict__ idx,
                                                 const float* __restrict__ cre,
                                                 const float* __restrict__ cim, int K,
                                                 int chunk, const int* __restrict__ base,
                                                 const int* __restrict__ off,
                                                 uint2* __restrict__ bucket) {
  __shared__ int lbase[4096];
  __shared__ int lcur[4096];
  const int c = blockIdx.x, tid = threadIdx.x;
#pragma unroll
  for (int l = 0; l < 4; ++l) {
    int k2 = tid + 1024 * l;
    lbase[k2] = base[(size_t)c * 4096 + k2] + off[k2];
    lcur[k2] = 0;
  }
  __syncthreads();
  const int j0 = c * chunk, j1 = min(j0 + chunk, K);
  for (int j = j0 + tid; j < j1; j += 1024) {
    int p = idx[j];
    int k2 = p & 4095;
    int r = atomicAdd(&lcur[k2], 1);          // LDS atomic: fast
    unsigned cr = f2bf(cre[j]), ci = f2bf(cim[j]);
    bucket[lbase[k2] + r] = make_uint2((unsigned)(p >> 12) | (cr << 16), ci << 16);
  }
}

// ---------------- B4: Y[t][k2] = sum c * X[t,k1], 1 wave per column, 2 t per lane.
__global__ __launch_bounds__(256) void spmm_col(const uint2* __restrict__ bucket,
                                                const int* __restrict__ off,
                                                const int* __restrict__ count,
                                                const unsigned* __restrict__ XTb,
                                                float2* __restrict__ Y) {
  const int lane = threadIdx.x & 63;
  const int k2 = blockIdx.x * 4 + (threadIdx.x >> 6);
  const int s = off[k2], n = count[k2];
  float ar0 = 0.f, ai0 = 0.f, ar1 = 0.f, ai1 = 0.f;
  for (int c = 0; c < n; c += 64) {
    int idx = c + lane;
    uint2 ec = (idx < n) ? bucket[s + idx] : make_uint2(0u, 0u);
#pragma unroll
    for (int j = 0; j < 64; ++j) {
      int w0 = __builtin_amdgcn_readlane((int)ec.x, j);
      int w1 = __builtin_amdgcn_readlane((int)ec.y, j);
      int k1 = w0 & 0xfff;
      int negm = (k1 > 2048) ? (int)0x80000000 : 0;
      int r = (k1 > 2048) ? 4096 - k1 : k1;
      int crb = w0 & 0xffff0000;
      float cr  = __int_as_float(crb);
      float ci  = __int_as_float(w1);
      float crs = __int_as_float(crb ^ negm);
      float cis = __int_as_float(w1 ^ negm);
      uint2 xv = *(const uint2*)(XTb + (size_t)r * NROW + 2 * lane);
      float xr0 = __int_as_float(xv.x << 16);
      float xi0 = __int_as_float(xv.x & 0xffff0000u);
      float xr1 = __int_as_float(xv.y << 16);
      float xi1 = __int_as_float(xv.y & 0xffff0000u);
      ar0 = fmaf(cr, xr0, ar0);  ar0 = fmaf(-cis, xi0, ar0);
      ai0 = fmaf(crs, xi0, ai0); ai0 = fmaf(ci, xr0, ai0);
      ar1 = fmaf(cr, xr1, ar1);  ar1 = fmaf(-cis, xi1, ar1);
      ai1 = fmaf(crs, xi1, ai1); ai1 = fmaf(ci, xr1, ai1);
    }
  }
  Y[(size_t)(2 * lane) * 4096 + k2]     = make_float2(ar0, ai0);
  Y[(size_t)(2 * lane + 1) * 4096 + k2] = make_float2(ar1, ai1);
}

// ---------------- Kernel C: out[t][n] += SCALE * Re(DFT-4096 of Y row). grid (128,2).
__global__ __launch_bounds__(1024) void dft_rows_y(const float2* __restrict__ Y,
                                                   float* __restrict__ out) {
  __shared__ float ysr[4096], ysi[4096];
  __shared__ float br[4096], bi[4096];
  __shared__ float2 w64[64];
  const int t = blockIdx.x, qi = blockIdx.y, tid = threadIdx.x;
  const float2* yrow = Y + (size_t)t * 4096;
#pragma unroll
  for (int l = 0; l < 4; ++l) {
    float2 v = yrow[tid + 1024 * l];
    ysr[tid + 1024 * l] = v.x; ysi[tid + 1024 * l] = v.y;
  }
  if (tid < 64) {
    float s, c; __sincosf(TWO_PI * (float)tid * (1.0f / 64.0f), &s, &c);
    w64[tid] = make_float2(c, s);
  }
  __syncthreads();
#pragma unroll
  for (int l = 0; l < 4; ++l) {
    int o = tid + 1024 * l, a = o >> 6, n1 = o & 63;
    float ar = 0.f, ai = 0.f;
    for (int b = 0; b < 64; ++b) {
      float yr = ysr[a + (b << 6)], yi = ysi[a + (b << 6)];
      float2 w = w64[(n1 * b) & 63];
      ar += yr * w.x - yi * w.y;
      ai += yr * w.y + yi * w.x;
    }
    float s, c; __sincosf((float)(n1 * a) * (TWO_PI / 4096.0f), &s, &c);
    br[o] = ar * c - ai * s;
    bi[o] = ar * s + ai * c;
  }
  __syncthreads();
  float* orow = out + (size_t)t * 4096;
  const int n1 = tid & 63;
  for (int n2 = qi * 32 + (tid >> 6); n2 < qi * 32 + 32; n2 += 16) {
    float acc = 0.f;
    for (int a = 0; a < 64; ++a) {
      float brv = br[(a << 6) + n1], biv = bi[(a << 6) + n1];
      float2 w = w64[(n2 * a) & 63];
      acc += brv * w.x - biv * w.y;
    }
    orow[n1 + (n2 << 6)] += acc * SCALE_A;
  }
}

// ---------------- x -> bf16 pre-convert
__global__ __launch_bounds__(256) void xcvt(const float* __restrict__ x,
                                            ushort_t* __restrict__ xbf) {
  size_t e = ((size_t)blockIdx.x * 256 + threadIdx.x) * 4;
  float4 v = *(const float4*)(x + e);
  unsigned lo = (unsigned)f2bf(v.x) | ((unsigned)f2bf(v.y) << 16);
  unsigned hi = (unsigned)f2bf(v.z) | ((unsigned)f2bf(v.w) << 16);
  *(uint2*)(xbf + e) = make_uint2(lo, hi);
}

// ---------------- base GEMM partials: part[kc][t][f], tile 128(t) x 64(f) x 64(k)
__global__ __launch_bounds__(256) void gemm_mfma_partial(const ushort_t* __restrict__ xbf,
                                                         const float* __restrict__ W,
                                                         float* __restrict__ part) {
  __shared__ ushort_t xs[128 * 64];
  __shared__ ushort_t wsl[64 * 64];
  const int f0 = blockIdx.x * 64;
  const int kc = blockIdx.y;
  const int tid = threadIdx.x;
  const int w = tid >> 6, lane = tid & 63;

  f32x4 acc[2][4];
#pragma unroll
  for (int i = 0; i < 2; ++i)
#pragma unroll
    for (int j = 0; j < 4; ++j) acc[i][j] = (f32x4){0.f, 0.f, 0.f, 0.f};

  const int kbeg = kc * 1024;
  for (int k0 = kbeg; k0 < kbeg + 1024; k0 += 64) {
#pragma unroll
    for (int l = 0; l < 4; ++l) {
      int s = tid + 256 * l, r = s >> 3, ks = s & 7;
      uint4 v = *(const uint4*)(xbf + (size_t)r * 4096 + k0 + ks * 8);
      *(uint4*)(&xs[r * 64 + ((ks ^ (r & 7)) << 3)]) = v;
    }
#pragma unroll
    for (int l = 0; l < 2; ++l) {
      int s = tid + 256 * l, r = s >> 3, ks = s & 7;
      const float* wp = W + (size_t)(f0 + r) * 4096 + k0 + ks * 8;
      float4 a = *(const float4*)(wp);
      float4 b = *(const float4*)(wp + 4);
      uint4 pk;
      pk.x = (unsigned)f2bf(a.x) | ((unsigned)f2bf(a.y) << 16);
      pk.y = (unsigned)f2bf(a.z) | ((unsigned)f2bf(a.w) << 16);
      pk.z = (unsigned)f2bf(b.x) | ((unsigned)f2bf(b.y) << 16);
      pk.w = (unsigned)f2bf(b.z) | ((unsigned)f2bf(b.w) << 16);
      *(uint4*)(&wsl[r * 64 + ((ks ^ (r & 7)) << 3)]) = pk;
    }
    __syncthreads();
#pragma unroll
    for (int kk = 0; kk < 2; ++kk) {
      int ksA = kk * 4 + (lane >> 4);
      short8 af[2], bfr[4];
#pragma unroll
      for (int mf = 0; mf < 2; ++mf) {
        int ra = w * 32 + mf * 16 + (lane & 15);
        af[mf] = *(const short8*)(&xs[ra * 64 + ((ksA ^ (ra & 7)) << 3)]);
      }
#pragma unroll
      for (int nf = 0; nf < 4; ++nf) {
        int rb = nf * 16 + (lane & 15);
        bfr[nf] = *(const short8*)(&wsl[rb * 64 + ((ksA ^ (rb & 7)) << 3)]);
      }
#pragma unroll
      for (int mf = 0; mf < 2; ++mf)
#pragma unroll
        for (int nf = 0; nf < 4; ++nf)
          acc[mf][nf] = __builtin_amdgcn_mfma_f32_16x16x32_bf16(af[mf], bfr[nf], acc[mf][nf], 0, 0, 0);
    }
    __syncthreads();
  }
  float* pb = part + ((size_t)kc << 19);
#pragma unroll
  for (int mf = 0; mf < 2; ++mf)
#pragma unroll
    for (int nf = 0; nf < 4; ++nf)
#pragma unroll
      for (int reg = 0; reg < 4; ++reg) {
        int row = w * 32 + mf * 16 + (lane >> 4) * 4 + reg;
        int col = f0 + nf * 16 + (lane & 15);
        pb[(size_t)row * 4096 + col] = acc[mf][nf][reg];
      }
}

// ---------------- reduce partials + bias -> out
__global__ __launch_bounds__(256) void reduce_bias(const float* __restrict__ part,
                                                   const float* __restrict__ b,
                                                   float* __restrict__ out) {
  size_t e = ((size_t)blockIdx.x * 256 + threadIdx.x) * 4;
  int f = (int)(e & 4095);
  float4 v0 = *(const float4*)(part + e);
  float4 v1 = *(const float4*)(part + e + (1ull << 19));
  float4 v2 = *(const float4*)(part + e + (2ull << 19));
  float4 v3 = *(const float4*)(part + e + (3ull << 19));
  float4 bb = *(const float4*)(b + f);
  float4 o;
  o.x = bb.x + v0.x + v1.x + v2.x + v3.x;
  o.y = bb.y + v0.y + v1.y + v2.y + v3.y;
  o.z = bb.z + v0.z + v1.z + v2.z + v3.z;
  o.w = bb.w + v0.w + v1.w + v2.w + v3.w;
  *(float4*)(out + e) = o;
}

extern "C" void kernel_launch(void* const* d_in, const int* in_sizes, int n_in,
                              void* d_out, int out_size, void* d_ws, size_t ws_size,
                              hipStream_t stream) {
  const float* x   = (const float*)d_in[0];
  const float* W   = (const float*)d_in[1];
  const float* b   = (const float*)d_in[2];
  const float* cre = (const float*)d_in[3];
  const float* cim = (const float*)d_in[4];
  const int* midx  = (const int*)d_in[5];
  const int K = in_sizes[3];
  float* out = (float*)d_out;
  const int chunk = (K + NCHUNK - 1) / NCHUNK;

  char* ws = (char*)d_ws;
  unsigned* XTb  = (unsigned*)(ws);                        // ~1.05 MB
  float2* Y      = (float2*)(ws + (size_t)(2 << 20));      // 4 MB
  uint2* bucket  = (uint2*)(ws + (size_t)(6 << 20));       // K*8 ~= 6.7 MB
  float*  part   = (float*)(ws + (size_t)(6 << 20));       // 8 MB, ALIASES bucket (bucket
                                                           // consumed by spmm_col first)
  int* cnt       = (int*)(ws + (size_t)(14 << 20));        // 256*4096*4 = 4 MB
  char* meta     = ws + (size_t)(18 << 20);
  int* tot = (int*)(meta);
  int* off = (int*)(meta + 16384);
  ushort_t* xbf = (ushort_t*)(ws + (size_t)(18 << 20) + 65536);  // 1 MB

  xcvt<<<512, 256, 0, stream>>>(x, xbf);
  dft_rows_x<<<dim3(NROW, 2), 1024, 0, stream>>>(x, XTb);
  count_chunks<<<NCHUNK, 1024, 0, stream>>>(midx, K, chunk, cnt);
  colscan<<<16, 256, 0, stream>>>(cnt, tot);
  scan4096<<<1, 1024, 0, stream>>>(tot, off);
  scatter2<<<NCHUNK, 1024, 0, stream>>>(midx, cre, cim, K, chunk, cnt, off, bucket);
  spmm_col<<<1024, 256, 0, stream>>>(bucket, off, tot, XTb, Y);
  gemm_mfma_partial<<<dim3(64, 4), 256, 0, stream>>>(xbf, W, part);
  reduce_bias<<<512, 256, 0, stream>>>(part, b, out);
  dft_rows_y<<<dim3(NROW, 2), 1024, 0, stream>>>(Y, out);
}

// Round 5
// 157.875 us; speedup vs baseline: 3.0403x; 1.0696x over previous
//
#include <hip/hip_runtime.h>

// LFMA adapter: out = x@W_base^T + b + x @ (alpha * Re(ifft2(scatter(c, mask_idx))))
// Factored: never materialize Delta_W.
//   X[t,k1] = sum_m x[t,m] e^{+2pi i m k1/4096}   (dft_rows_x; Hermitian: store k<=2048, bf16)
//   Y[t,k2] = sum_{nz (k1,k2,c)} c * X[t,k1]      (bucketed sparse, readlane-broadcast spmm)
//   out2[t,n] = SCALE * Re( sum_k2 Y[t,k2] e^{+2pi i n k2/4096} )   (dft_rows_y, WRITES out)
// Bucketing: deterministic two-pass (LDS histograms + column scan), no global atomics.
// Base GEMM (R5): kc=8 K-split, double-buffered LDS, issue-early/write-late 2-phase
// pipeline (1 barrier/K-step); reduce_bias accumulates out += b + sum(partials).

#define TWO_PI 6.28318530717958647692f
constexpr int NROW = 128;
constexpr float SCALE_A = 16.0f / 16777216.0f;
constexpr int NCHUNK = 256;
constexpr int KC = 8;                      // K-split chunks for base GEMM

typedef unsigned short ushort_t;
using short8 = __attribute__((ext_vector_type(8))) short;
using f32x4  = __attribute__((ext_vector_type(4))) float;

__device__ __forceinline__ ushort_t f2bf(float f) {
  unsigned u = __float_as_uint(f);
  u = (u + 0x7FFFu + ((u >> 16) & 1u)) >> 16;   // RNE
  return (ushort_t)u;
}

// ---------------- Kernel A: XTb[k][t] packed bf16 complex, k in [0,2048] only (Hermitian)
__global__ __launch_bounds__(1024) void dft_rows_x(const float* __restrict__ x,
                                                   unsigned* __restrict__ XTb) {
  __shared__ float xs[4096];
  __shared__ float br[4096], bi[4096];
  __shared__ float2 w64[64];
  const int t = blockIdx.x, qi = blockIdx.y, tid = threadIdx.x;
  const float* xrow = x + (size_t)t * 4096;
#pragma unroll
  for (int l = 0; l < 4; ++l) xs[tid + 1024 * l] = xrow[tid + 1024 * l];
  if (tid < 64) {
    float s, c; __sincosf(TWO_PI * (float)tid * (1.0f / 64.0f), &s, &c);
    w64[tid] = make_float2(c, s);          // W64^j = e^{+2pi i j/64}
  }
  __syncthreads();
#pragma unroll
  for (int l = 0; l < 4; ++l) {
    int o = tid + 1024 * l, m1 = o >> 6, k1 = o & 63;
    float ar = 0.f, ai = 0.f;
    for (int m2 = 0; m2 < 64; ++m2) {
      float xv = xs[m1 + (m2 << 6)];
      float2 w = w64[(m2 * k1) & 63];
      ar = fmaf(xv, w.x, ar); ai = fmaf(xv, w.y, ai);
    }
    float s, c; __sincosf((float)(m1 * k1) * (TWO_PI / 4096.0f), &s, &c);
    br[o] = ar * c - ai * s;
    bi[o] = ar * s + ai * c;
  }
  __syncthreads();
  const int k2lo = qi * 16, k2hi = k2lo + 16 + qi;
  const int k1 = tid & 63;
  for (int k2 = k2lo + (tid >> 6); k2 < k2hi; k2 += 16) {
    int k = k1 + (k2 << 6);
    if (k <= 2048) {
      float xr = 0.f, xi = 0.f;
      for (int m1 = 0; m1 < 64; ++m1) {
        float brv = br[(m1 << 6) + k1], biv = bi[(m1 << 6) + k1];
        float2 w = w64[(m1 * k2) & 63];
        xr += brv * w.x - biv * w.y;
        xi += brv * w.y + biv * w.x;
      }
      XTb[(size_t)k * NROW + t] = (unsigned)f2bf(xr) | ((unsigned)f2bf(xi) << 16);
    }
  }
}

// ---------------- S1: per-chunk LDS histogram of k2
__global__ __launch_bounds__(1024) void count_chunks(const int* __restrict__ idx, int K,
                                                     int chunk, int* __restrict__ cnt) {
  __shared__ int h[4096];
  const int c = blockIdx.x, tid = threadIdx.x;
#pragma unroll
  for (int l = 0; l < 4; ++l) h[tid + 1024 * l] = 0;
  __syncthreads();
  const int j0 = c * chunk, j1 = min(j0 + chunk, K);
  for (int j = j0 + tid; j < j1; j += 1024) atomicAdd(&h[idx[j] & 4095], 1);
  __syncthreads();
#pragma unroll
  for (int l = 0; l < 4; ++l) cnt[(size_t)c * 4096 + tid + 1024 * l] = h[tid + 1024 * l];
}

// ---------------- S2: per-column exclusive scan over chunks (in place) + totals
__global__ __launch_bounds__(256) void colscan(int* __restrict__ cnt, int* __restrict__ tot) {
  const int k2 = blockIdx.x * 256 + threadIdx.x;
  int run = 0;
  for (int c8 = 0; c8 < NCHUNK; c8 += 8) {
    int v[8];
#pragma unroll
    for (int i = 0; i < 8; ++i) v[i] = cnt[(size_t)(c8 + i) * 4096 + k2];
#pragma unroll
    for (int i = 0; i < 8; ++i) {
      cnt[(size_t)(c8 + i) * 4096 + k2] = run;
      run += v[i];
    }
  }
  tot[k2] = run;
}

// ---------------- B2: exclusive scan over 4096 totals (single block)
__global__ __launch_bounds__(1024) void scan4096(const int* __restrict__ count,
                                                 int* __restrict__ off) {
  __shared__ int s[4096];
  int tid = threadIdx.x;
#pragma unroll
  for (int l = 0; l < 4; ++l) s[tid + 1024 * l] = count[tid + 1024 * l];
  __syncthreads();
  for (int d = 1; d < 4096; d <<= 1) {
    int v[4];
#pragma unroll
    for (int l = 0; l < 4; ++l) {
      int i = tid + 1024 * l;
      v[l] = s[i] + ((i >= d) ? s[i - d] : 0);
    }
    __syncthreads();
#pragma unroll
    for (int l = 0; l < 4; ++l) s[tid + 1024 * l] = v[l];
    __syncthreads();
  }
#pragma unroll
  for (int l = 0; l < 4; ++l) {
    int i = tid + 1024 * l;
    off[i] = s[i] - count[i];
  }
}

// ---------------- S3: scatter with LDS-rank (no returning global atomics)
__global__ __launch_bounds__(1024) void scatter2(const int* __restrict__ idx,
                                                 const float* __restrict__ cre,
                                                 const float* __restrict__ cim, int K,
                                                 int chunk, const int* __restrict__ base,
                                                 const int* __restrict__ off,
                                                 uint2* __restrict__ bucket) {
  __shared__ int lbase[4096];
  __shared__ int lcur[4096];
  const int c = blockIdx.x, tid = threadIdx.x;
#pragma unroll
  for (int l = 0; l < 4; ++l) {
    int k2 = tid + 1024 * l;
    lbase[k2] = base[(size_t)c * 4096 + k2] + off[k2];
    lcur[k2] = 0;
  }
  __syncthreads();
  const int j0 = c * chunk, j1 = min(j0 + chunk, K);
  for (int j = j0 + tid; j < j1; j += 1024) {
    int p = idx[j];
    int k2 = p & 4095;
    int r = atomicAdd(&lcur[k2], 1);          // LDS atomic: fast
    unsigned cr = f2bf(cre[j]), ci = f2bf(cim[j]);
    bucket[lbase[k2] + r] = make_uint2((unsigned)(p >> 12) | (cr << 16), ci << 16);
  }
}

// ---------------- B4: Y[t][k2] = sum c * X[t,k1], 1 wave per column, 2 t per lane.
__global__ __launch_bounds__(256) void spmm_col(const uint2* __restrict__ bucket,
                                                const int* __restrict__ off,
                                                const int* __restrict__ count,
                                                const unsigned* __restrict__ XTb,
                                                float2* __restrict__ Y) {
  const int lane = threadIdx.x & 63;
  const int k2 = blockIdx.x * 4 + (threadIdx.x >> 6);
  const int s = off[k2], n = count[k2];
  float ar0 = 0.f, ai0 = 0.f, ar1 = 0.f, ai1 = 0.f;
  for (int c = 0; c < n; c += 64) {
    int idx = c + lane;
    uint2 ec = (idx < n) ? bucket[s + idx] : make_uint2(0u, 0u);
#pragma unroll
    for (int j = 0; j < 64; ++j) {
      int w0 = __builtin_amdgcn_readlane((int)ec.x, j);
      int w1 = __builtin_amdgcn_readlane((int)ec.y, j);
      int k1 = w0 & 0xfff;
      int negm = (k1 > 2048) ? (int)0x80000000 : 0;
      int r = (k1 > 2048) ? 4096 - k1 : k1;
      int crb = w0 & 0xffff0000;
      float cr  = __int_as_float(crb);
      float ci  = __int_as_float(w1);
      float crs = __int_as_float(crb ^ negm);
      float cis = __int_as_float(w1 ^ negm);
      uint2 xv = *(const uint2*)(XTb + (size_t)r * NROW + 2 * lane);
      float xr0 = __int_as_float(xv.x << 16);
      float xi0 = __int_as_float(xv.x & 0xffff0000u);
      float xr1 = __int_as_float(xv.y << 16);
      float xi1 = __int_as_float(xv.y & 0xffff0000u);
      ar0 = fmaf(cr, xr0, ar0);  ar0 = fmaf(-cis, xi0, ar0);
      ai0 = fmaf(crs, xi0, ai0); ai0 = fmaf(ci, xr0, ai0);
      ar1 = fmaf(cr, xr1, ar1);  ar1 = fmaf(-cis, xi1, ar1);
      ai1 = fmaf(crs, xi1, ai1); ai1 = fmaf(ci, xr1, ai1);
    }
  }
  Y[(size_t)(2 * lane) * 4096 + k2]     = make_float2(ar0, ai0);
  Y[(size_t)(2 * lane + 1) * 4096 + k2] = make_float2(ar1, ai1);
}

// ---------------- Kernel C: out[t][n] = SCALE * Re(DFT-4096 of Y row). grid (128,2).
// NOTE: WRITES out (runs before gemm/reduce; reduce_bias accumulates on top).
__global__ __launch_bounds__(1024) void dft_rows_y(const float2* __restrict__ Y,
                                                   float* __restrict__ out) {
  __shared__ float ysr[4096], ysi[4096];
  __shared__ float br[4096], bi[4096];
  __shared__ float2 w64[64];
  const int t = blockIdx.x, qi = blockIdx.y, tid = threadIdx.x;
  const float2* yrow = Y + (size_t)t * 4096;
#pragma unroll
  for (int l = 0; l < 4; ++l) {
    float2 v = yrow[tid + 1024 * l];
    ysr[tid + 1024 * l] = v.x; ysi[tid + 1024 * l] = v.y;
  }
  if (tid < 64) {
    float s, c; __sincosf(TWO_PI * (float)tid * (1.0f / 64.0f), &s, &c);
    w64[tid] = make_float2(c, s);
  }
  __syncthreads();
#pragma unroll
  for (int l = 0; l < 4; ++l) {
    int o = tid + 1024 * l, a = o >> 6, n1 = o & 63;
    float ar = 0.f, ai = 0.f;
    for (int b = 0; b < 64; ++b) {
      float yr = ysr[a + (b << 6)], yi = ysi[a + (b << 6)];
      float2 w = w64[(n1 * b) & 63];
      ar += yr * w.x - yi * w.y;
      ai += yr * w.y + yi * w.x;
    }
    float s, c; __sincosf((float)(n1 * a) * (TWO_PI / 4096.0f), &s, &c);
    br[o] = ar * c - ai * s;
    bi[o] = ar * s + ai * c;
  }
  __syncthreads();
  float* orow = out + (size_t)t * 4096;
  const int n1 = tid & 63;
  for (int n2 = qi * 32 + (tid >> 6); n2 < qi * 32 + 32; n2 += 16) {
    float acc = 0.f;
    for (int a = 0; a < 64; ++a) {
      float brv = br[(a << 6) + n1], biv = bi[(a << 6) + n1];
      float2 w = w64[(n2 * a) & 63];
      acc += brv * w.x - biv * w.y;
    }
    orow[n1 + (n2 << 6)] = acc * SCALE_A;
  }
}

// ---------------- x -> bf16 pre-convert
__global__ __launch_bounds__(256) void xcvt(const float* __restrict__ x,
                                            ushort_t* __restrict__ xbf) {
  size_t e = ((size_t)blockIdx.x * 256 + threadIdx.x) * 4;
  float4 v = *(const float4*)(x + e);
  unsigned lo = (unsigned)f2bf(v.x) | ((unsigned)f2bf(v.y) << 16);
  unsigned hi = (unsigned)f2bf(v.z) | ((unsigned)f2bf(v.w) << 16);
  *(uint2*)(xbf + e) = make_uint2(lo, hi);
}

// ---------------- base GEMM partials: part[kc][t][f], tile 128(t) x 64(f) x 64(k)
// grid (64 f-tiles, KC=8 k-chunks) = 512 blocks (2/CU), double-buffered LDS,
// issue-early/write-late 2-phase pipeline, 1 barrier per K-step.
__global__ __launch_bounds__(256) void gemm_mfma_partial(const ushort_t* __restrict__ xbf,
                                                         const float* __restrict__ W,
                                                         float* __restrict__ part) {
  __shared__ ushort_t xs[2][128 * 64];   // 2 x 16 KB
  __shared__ ushort_t wsl[2][64 * 64];   // 2 x 8 KB
  const int f0 = blockIdx.x * 64;
  const int kc = blockIdx.y;
  const int tid = threadIdx.x;
  const int w = tid >> 6, lane = tid & 63;

  f32x4 acc[2][4];
#pragma unroll
  for (int i = 0; i < 2; ++i)
#pragma unroll
    for (int j = 0; j < 4; ++j) acc[i][j] = (f32x4){0.f, 0.f, 0.f, 0.f};

  uint4 rx[4];
  float4 rwa[2], rwb[2];
  const int kbeg = kc * 512;

  // prologue: issue step-0 loads
#pragma unroll
  for (int l = 0; l < 4; ++l) {
    int s = tid + 256 * l, r = s >> 3, ks = s & 7;
    rx[l] = *(const uint4*)(xbf + (size_t)r * 4096 + kbeg + ks * 8);
  }
#pragma unroll
  for (int l = 0; l < 2; ++l) {
    int s = tid + 256 * l, r = s >> 3, ks = s & 7;
    const float* wp = W + (size_t)(f0 + r) * 4096 + kbeg + ks * 8;
    rwa[l] = *(const float4*)(wp);
    rwb[l] = *(const float4*)(wp + 4);
  }

  int cur = 0;
  for (int st = 0; st < 8; ++st) {
    // write-late: staged regs -> LDS[cur] (XOR-swizzled 16B slots)
#pragma unroll
    for (int l = 0; l < 4; ++l) {
      int s = tid + 256 * l, r = s >> 3, ks = s & 7;
      *(uint4*)(&xs[cur][r * 64 + ((ks ^ (r & 7)) << 3)]) = rx[l];
    }
#pragma unroll
    for (int l = 0; l < 2; ++l) {
      int s = tid + 256 * l, r = s >> 3, ks = s & 7;
      uint4 pk;
      pk.x = (unsigned)f2bf(rwa[l].x) | ((unsigned)f2bf(rwa[l].y) << 16);
      pk.y = (unsigned)f2bf(rwa[l].z) | ((unsigned)f2bf(rwa[l].w) << 16);
      pk.z = (unsigned)f2bf(rwb[l].x) | ((unsigned)f2bf(rwb[l].y) << 16);
      pk.w = (unsigned)f2bf(rwb[l].z) | ((unsigned)f2bf(rwb[l].w) << 16);
      *(uint4*)(&wsl[cur][r * 64 + ((ks ^ (r & 7)) << 3)]) = pk;
    }
    __syncthreads();
    // issue-early: next step's global loads overlap this step's ds_read+MFMA
    if (st < 7) {
      const int k0 = kbeg + (st + 1) * 64;
#pragma unroll
      for (int l = 0; l < 4; ++l) {
        int s = tid + 256 * l, r = s >> 3, ks = s & 7;
        rx[l] = *(const uint4*)(xbf + (size_t)r * 4096 + k0 + ks * 8);
      }
#pragma unroll
      for (int l = 0; l < 2; ++l) {
        int s = tid + 256 * l, r = s >> 3, ks = s & 7;
        const float* wp = W + (size_t)(f0 + r) * 4096 + k0 + ks * 8;
        rwa[l] = *(const float4*)(wp);
        rwb[l] = *(const float4*)(wp + 4);
      }
    }
#pragma unroll
    for (int kk = 0; kk < 2; ++kk) {
      int ksA = kk * 4 + (lane >> 4);
      short8 af[2], bfr[4];
#pragma unroll
      for (int mf = 0; mf < 2; ++mf) {
        int ra = w * 32 + mf * 16 + (lane & 15);
        af[mf] = *(const short8*)(&xs[cur][ra * 64 + ((ksA ^ (ra & 7)) << 3)]);
      }
#pragma unroll
      for (int nf = 0; nf < 4; ++nf) {
        int rb = nf * 16 + (lane & 15);
        bfr[nf] = *(const short8*)(&wsl[cur][rb * 64 + ((ksA ^ (rb & 7)) << 3)]);
      }
#pragma unroll
      for (int mf = 0; mf < 2; ++mf)
#pragma unroll
        for (int nf = 0; nf < 4; ++nf)
          acc[mf][nf] = __builtin_amdgcn_mfma_f32_16x16x32_bf16(af[mf], bfr[nf], acc[mf][nf], 0, 0, 0);
    }
    cur ^= 1;
  }
  float* pb = part + ((size_t)kc << 19);
#pragma unroll
  for (int mf = 0; mf < 2; ++mf)
#pragma unroll
    for (int nf = 0; nf < 4; ++nf)
#pragma unroll
      for (int reg = 0; reg < 4; ++reg) {
        int row = w * 32 + mf * 16 + (lane >> 4) * 4 + reg;
        int col = f0 + nf * 16 + (lane & 15);
        pb[(size_t)row * 4096 + col] = acc[mf][nf][reg];
      }
}

// ---------------- out += bias + sum of KC partials (out already holds dft_y result)
__global__ __launch_bounds__(256) void reduce_bias(const float* __restrict__ part,
                                                   const float* __restrict__ b,
                                                   float* __restrict__ out) {
  size_t e = ((size_t)blockIdx.x * 256 + threadIdx.x) * 4;
  int f = (int)(e & 4095);
  float4 o  = *(const float4*)(out + e);
  float4 bb = *(const float4*)(b + f);
  float sx = o.x + bb.x, sy = o.y + bb.y, sz = o.z + bb.z, sw = o.w + bb.w;
#pragma unroll
  for (int i = 0; i < KC; ++i) {
    float4 v = *(const float4*)(part + e + ((size_t)i << 19));
    sx += v.x; sy += v.y; sz += v.z; sw += v.w;
  }
  *(float4*)(out + e) = make_float4(sx, sy, sz, sw);
}

extern "C" void kernel_launch(void* const* d_in, const int* in_sizes, int n_in,
                              void* d_out, int out_size, void* d_ws, size_t ws_size,
                              hipStream_t stream) {
  const float* x   = (const float*)d_in[0];
  const float* W   = (const float*)d_in[1];
  const float* b   = (const float*)d_in[2];
  const float* cre = (const float*)d_in[3];
  const float* cim = (const float*)d_in[4];
  const int* midx  = (const int*)d_in[5];
  const int K = in_sizes[3];
  float* out = (float*)d_out;
  const int chunk = (K + NCHUNK - 1) / NCHUNK;

  char* ws = (char*)d_ws;
  unsigned* XTb  = (unsigned*)(ws);                        // ~1.05 MB
  float2* Y      = (float2*)(ws + (size_t)(2 << 20));      // 4 MB
  uint2* bucket  = (uint2*)(ws + (size_t)(6 << 20));       // K*8 ~= 6.7 MB (ends <13M)
  int* cnt       = (int*)(ws + (size_t)(13 << 20));        // 4 MB (ends 17M)
  char* meta     = ws + (size_t)(17 << 20);                // tot/off 32 KB
  int* tot = (int*)(meta);
  int* off = (int*)(meta + 16384);
  ushort_t* xbf  = (ushort_t*)(ws + (size_t)(18 << 20));   // 1 MB (ends 19M)
  float* part    = (float*)(ws + (size_t)(2 << 20));       // KC*2MB = 16 MB (ends 18M);
  // part ALIASES Y/bucket/cnt/meta — all fully consumed before gemm runs (dft_y,
  // spmm, scatter precede it in stream order). xbf/XTb live outside its range.

  xcvt<<<512, 256, 0, stream>>>(x, xbf);
  dft_rows_x<<<dim3(NROW, 2), 1024, 0, stream>>>(x, XTb);
  count_chunks<<<NCHUNK, 1024, 0, stream>>>(midx, K, chunk, cnt);
  colscan<<<16, 256, 0, stream>>>(cnt, tot);
  scan4096<<<1, 1024, 0, stream>>>(tot, off);
  scatter2<<<NCHUNK, 1024, 0, stream>>>(midx, cre, cim, K, chunk, cnt, off, bucket);
  spmm_col<<<1024, 256, 0, stream>>>(bucket, off, tot, XTb, Y);
  dft_rows_y<<<dim3(NROW, 2), 1024, 0, stream>>>(Y, out);      // writes out2
  gemm_mfma_partial<<<dim3(64, KC), 256, 0, stream>>>(xbf, W, part);
  reduce_bias<<<512, 256, 0, stream>>>(part, b, out);          // out += b + sum(part)
}

// Round 6
// 141.439 us; speedup vs baseline: 3.3936x; 1.1162x over previous
//
#include <hip/hip_runtime.h>

// LFMA adapter: out = x@W_base^T + b + x @ (alpha * Re(ifft2(scatter(c, mask_idx))))
// Factored: never materialize Delta_W.
//   X[t,k1] = sum_m x[t,m] e^{+2pi i m k1/4096}   (dft_rows_x; Hermitian: store k<=2048, bf16)
//   Y[t,k2] = sum_{nz (k1,k2,c)} c * X[t,k1]      (bucketed sparse, readlane-broadcast spmm)
//   out2[t,n] = SCALE * Re( sum_k2 Y[t,k2] e^{+2pi i n k2/4096} )   (dft_rows_y, WRITES out)
// R6: spmm 2 waves/column (TLP); DFT blocks split phase-1 by output residue (no dup).
// Bucketing: deterministic two-pass (LDS histograms + column scan), no global atomics.
// Base GEMM: kc=8 K-split, dbuf LDS, issue-early/write-late pipeline; reduce_bias sums.

#define TWO_PI 6.28318530717958647692f
constexpr int NROW = 128;
constexpr float SCALE_A = 16.0f / 16777216.0f;
constexpr int NCHUNK = 256;
constexpr int KC = 8;

typedef unsigned short ushort_t;
using short8 = __attribute__((ext_vector_type(8))) short;
using f32x4  = __attribute__((ext_vector_type(4))) float;

__device__ __forceinline__ ushort_t f2bf(float f) {
  unsigned u = __float_as_uint(f);
  u = (u + 0x7FFFu + ((u >> 16) & 1u)) >> 16;   // RNE
  return (ushort_t)u;
}

// ---------------- Kernel A: XTb[k][t] packed bf16 complex, k in [0,2048] (Hermitian).
// grid (128, 2): block qi handles k1 (mod-64 residue) in [qi*32, qi*32+32).
__global__ __launch_bounds__(1024) void dft_rows_x(const float* __restrict__ x,
                                                   unsigned* __restrict__ XTb) {
  __shared__ float xs[4096];
  __shared__ float br[2048], bi[2048];
  __shared__ float2 w64[64];
  const int t = blockIdx.x, qi = blockIdx.y, tid = threadIdx.x;
  const float* xrow = x + (size_t)t * 4096;
#pragma unroll
  for (int l = 0; l < 4; ++l) xs[tid + 1024 * l] = xrow[tid + 1024 * l];
  if (tid < 64) {
    float s, c; __sincosf(TWO_PI * (float)tid * (1.0f / 64.0f), &s, &c);
    w64[tid] = make_float2(c, s);          // W64^j = e^{+2pi i j/64}
  }
  __syncthreads();
  // phase 1: B[m1][k1] for k1 in this block's residue range only
#pragma unroll
  for (int l = 0; l < 2; ++l) {
    int o = tid + 1024 * l, m1 = o >> 5, k1l = o & 31, k1 = qi * 32 + k1l;
    float ar = 0.f, ai = 0.f;
    for (int m2 = 0; m2 < 64; ++m2) {
      float xv = xs[m1 + (m2 << 6)];
      float2 w = w64[(m2 * k1) & 63];
      ar = fmaf(xv, w.x, ar); ai = fmaf(xv, w.y, ai);
    }
    float s, c; __sincosf((float)(m1 * k1) * (TWO_PI / 4096.0f), &s, &c);
    br[(m1 << 5) + k1l] = ar * c - ai * s;
    bi[(m1 << 5) + k1l] = ar * s + ai * c;
  }
  __syncthreads();
  // phase 2: k = k1 + 64*k2, k2 in [0,32) -> covers all k<2048 with this residue
  {
    const int k1l = tid & 31, k2 = tid >> 5;
    const int k = qi * 32 + k1l + (k2 << 6);
    float xr = 0.f, xi = 0.f;
    for (int m1 = 0; m1 < 64; ++m1) {
      float brv = br[(m1 << 5) + k1l], biv = bi[(m1 << 5) + k1l];
      float2 w = w64[(m1 * k2) & 63];
      xr += brv * w.x - biv * w.y;
      xi += brv * w.y + biv * w.x;
    }
    XTb[(size_t)k * NROW + t] = (unsigned)f2bf(xr) | ((unsigned)f2bf(xi) << 16);
    if (qi == 0 && tid == 0) {             // k = 2048: w64^(32*m1) = (-1)^m1
      float xr2 = 0.f, xi2 = 0.f;
      for (int m1 = 0; m1 < 64; ++m1) {
        float sgn = (m1 & 1) ? -1.f : 1.f;
        xr2 = fmaf(sgn, br[m1 << 5], xr2);
        xi2 = fmaf(sgn, bi[m1 << 5], xi2);
      }
      XTb[(size_t)2048 * NROW + t] = (unsigned)f2bf(xr2) | ((unsigned)f2bf(xi2) << 16);
    }
  }
}

// ---------------- S1: per-chunk LDS histogram of k2
__global__ __launch_bounds__(1024) void count_chunks(const int* __restrict__ idx, int K,
                                                     int chunk, int* __restrict__ cnt) {
  __shared__ int h[4096];
  const int c = blockIdx.x, tid = threadIdx.x;
#pragma unroll
  for (int l = 0; l < 4; ++l) h[tid + 1024 * l] = 0;
  __syncthreads();
  const int j0 = c * chunk, j1 = min(j0 + chunk, K);
  for (int j = j0 + tid; j < j1; j += 1024) atomicAdd(&h[idx[j] & 4095], 1);
  __syncthreads();
#pragma unroll
  for (int l = 0; l < 4; ++l) cnt[(size_t)c * 4096 + tid + 1024 * l] = h[tid + 1024 * l];
}

// ---------------- S2: per-column exclusive scan over chunks (in place) + totals
__global__ __launch_bounds__(256) void colscan(int* __restrict__ cnt, int* __restrict__ tot) {
  const int k2 = blockIdx.x * 256 + threadIdx.x;
  int run = 0;
  for (int c8 = 0; c8 < NCHUNK; c8 += 8) {
    int v[8];
#pragma unroll
    for (int i = 0; i < 8; ++i) v[i] = cnt[(size_t)(c8 + i) * 4096 + k2];
#pragma unroll
    for (int i = 0; i < 8; ++i) {
      cnt[(size_t)(c8 + i) * 4096 + k2] = run;
      run += v[i];
    }
  }
  tot[k2] = run;
}

// ---------------- B2: exclusive scan over 4096 totals (single block)
__global__ __launch_bounds__(1024) void scan4096(const int* __restrict__ count,
                                                 int* __restrict__ off) {
  __shared__ int s[4096];
  int tid = threadIdx.x;
#pragma unroll
  for (int l = 0; l < 4; ++l) s[tid + 1024 * l] = count[tid + 1024 * l];
  __syncthreads();
  for (int d = 1; d < 4096; d <<= 1) {
    int v[4];
#pragma unroll
    for (int l = 0; l < 4; ++l) {
      int i = tid + 1024 * l;
      v[l] = s[i] + ((i >= d) ? s[i - d] : 0);
    }
    __syncthreads();
#pragma unroll
    for (int l = 0; l < 4; ++l) s[tid + 1024 * l] = v[l];
    __syncthreads();
  }
#pragma unroll
  for (int l = 0; l < 4; ++l) {
    int i = tid + 1024 * l;
    off[i] = s[i] - count[i];
  }
}

// ---------------- S3: scatter with LDS-rank (no returning global atomics)
__global__ __launch_bounds__(1024) void scatter2(const int* __restrict__ idx,
                                                 const float* __restrict__ cre,
                                                 const float* __restrict__ cim, int K,
                                                 int chunk, const int* __restrict__ base,
                                                 const int* __restrict__ off,
                                                 uint2* __restrict__ bucket) {
  __shared__ int lbase[4096];
  __shared__ int lcur[4096];
  const int c = blockIdx.x, tid = threadIdx.x;
#pragma unroll
  for (int l = 0; l < 4; ++l) {
    int k2 = tid + 1024 * l;
    lbase[k2] = base[(size_t)c * 4096 + k2] + off[k2];
    lcur[k2] = 0;
  }
  __syncthreads();
  const int j0 = c * chunk, j1 = min(j0 + chunk, K);
  for (int j = j0 + tid; j < j1; j += 1024) {
    int p = idx[j];
    int k2 = p & 4095;
    int r = atomicAdd(&lcur[k2], 1);          // LDS atomic: fast
    unsigned cr = f2bf(cre[j]), ci = f2bf(cim[j]);
    bucket[lbase[k2] + r] = make_uint2((unsigned)(p >> 12) | (cr << 16), ci << 16);
  }
}

// ---------------- B4: Y[t][k2] = sum c * X[t,k1]. 2 waves per column (TLP),
// 2 columns per 256-thr block; LDS pair-reduction at the end.
__global__ __launch_bounds__(256) void spmm_col(const uint2* __restrict__ bucket,
                                                const int* __restrict__ off,
                                                const int* __restrict__ count,
                                                const unsigned* __restrict__ XTb,
                                                float2* __restrict__ Y) {
  __shared__ float4 red[2][64];
  const int lane = threadIdx.x & 63;
  const int wid = threadIdx.x >> 6;
  const int colsel = wid >> 1, half = wid & 1;
  const int k2 = blockIdx.x * 2 + colsel;
  const int s = off[k2], n = count[k2];
  float ar0 = 0.f, ai0 = 0.f, ar1 = 0.f, ai1 = 0.f;
  for (int c = half * 64; c < n; c += 128) {
    int idx = c + lane;
    uint2 ec = (idx < n) ? bucket[s + idx] : make_uint2(0u, 0u);
#pragma unroll
    for (int j = 0; j < 64; ++j) {
      int w0 = __builtin_amdgcn_readlane((int)ec.x, j);
      int w1 = __builtin_amdgcn_readlane((int)ec.y, j);
      int k1 = w0 & 0xfff;
      int negm = (k1 > 2048) ? (int)0x80000000 : 0;
      int r = (k1 > 2048) ? 4096 - k1 : k1;
      int crb = w0 & 0xffff0000;
      float cr  = __int_as_float(crb);
      float ci  = __int_as_float(w1);
      float crs = __int_as_float(crb ^ negm);
      float cis = __int_as_float(w1 ^ negm);
      uint2 xv = *(const uint2*)(XTb + (size_t)r * NROW + 2 * lane);
      float xr0 = __int_as_float(xv.x << 16);
      float xi0 = __int_as_float(xv.x & 0xffff0000u);
      float xr1 = __int_as_float(xv.y << 16);
      float xi1 = __int_as_float(xv.y & 0xffff0000u);
      ar0 = fmaf(cr, xr0, ar0);  ar0 = fmaf(-cis, xi0, ar0);
      ai0 = fmaf(crs, xi0, ai0); ai0 = fmaf(ci, xr0, ai0);
      ar1 = fmaf(cr, xr1, ar1);  ar1 = fmaf(-cis, xi1, ar1);
      ai1 = fmaf(crs, xi1, ai1); ai1 = fmaf(ci, xr1, ai1);
    }
  }
  if (half == 1) red[colsel][lane] = make_float4(ar0, ai0, ar1, ai1);
  __syncthreads();
  if (half == 0) {
    float4 o = red[colsel][lane];
    ar0 += o.x; ai0 += o.y; ar1 += o.z; ai1 += o.w;
    Y[(size_t)(2 * lane) * 4096 + k2]     = make_float2(ar0, ai0);
    Y[(size_t)(2 * lane + 1) * 4096 + k2] = make_float2(ar1, ai1);
  }
}

// ---------------- Kernel C: out[t][n] = SCALE * Re(DFT-4096 of Y row). grid (128,2).
// Block qi handles n1 (mod-64 residue) in [qi*32, qi*32+32). WRITES out.
__global__ __launch_bounds__(1024) void dft_rows_y(const float2* __restrict__ Y,
                                                   float* __restrict__ out) {
  __shared__ float ysr[4096], ysi[4096];
  __shared__ float br[2048], bi[2048];
  __shared__ float2 w64[64];
  const int t = blockIdx.x, qi = blockIdx.y, tid = threadIdx.x;
  const float2* yrow = Y + (size_t)t * 4096;
#pragma unroll
  for (int l = 0; l < 4; ++l) {
    float2 v = yrow[tid + 1024 * l];
    ysr[tid + 1024 * l] = v.x; ysi[tid + 1024 * l] = v.y;
  }
  if (tid < 64) {
    float s, c; __sincosf(TWO_PI * (float)tid * (1.0f / 64.0f), &s, &c);
    w64[tid] = make_float2(c, s);
  }
  __syncthreads();
  // phase 1: B[a][n1] for n1 in this block's residue range
#pragma unroll
  for (int l = 0; l < 2; ++l) {
    int o = tid + 1024 * l, a = o >> 5, n1l = o & 31, n1 = qi * 32 + n1l;
    float ar = 0.f, ai = 0.f;
    for (int b = 0; b < 64; ++b) {
      float yr = ysr[a + (b << 6)], yi = ysi[a + (b << 6)];
      float2 w = w64[(n1 * b) & 63];
      ar += yr * w.x - yi * w.y;
      ai += yr * w.y + yi * w.x;
    }
    float s, c; __sincosf((float)(n1 * a) * (TWO_PI / 4096.0f), &s, &c);
    br[(a << 5) + n1l] = ar * c - ai * s;
    bi[(a << 5) + n1l] = ar * s + ai * c;
  }
  __syncthreads();
  // phase 2: n = n1 + 64*n2, n2 in [0,64)
  float* orow = out + (size_t)t * 4096;
  const int n1l = tid & 31;
  const int n1 = qi * 32 + n1l;
#pragma unroll
  for (int l = 0; l < 2; ++l) {
    int n2 = (tid >> 5) + 32 * l;
    float acc = 0.f;
    for (int a = 0; a < 64; ++a) {
      float brv = br[(a << 5) + n1l], biv = bi[(a << 5) + n1l];
      float2 w = w64[(n2 * a) & 63];
      acc += brv * w.x - biv * w.y;
    }
    orow[n1 + (n2 << 6)] = acc * SCALE_A;
  }
}

// ---------------- x -> bf16 pre-convert
__global__ __launch_bounds__(256) void xcvt(const float* __restrict__ x,
                                            ushort_t* __restrict__ xbf) {
  size_t e = ((size_t)blockIdx.x * 256 + threadIdx.x) * 4;
  float4 v = *(const float4*)(x + e);
  unsigned lo = (unsigned)f2bf(v.x) | ((unsigned)f2bf(v.y) << 16);
  unsigned hi = (unsigned)f2bf(v.z) | ((unsigned)f2bf(v.w) << 16);
  *(uint2*)(xbf + e) = make_uint2(lo, hi);
}

// ---------------- base GEMM partials: part[kc][t][f], tile 128(t) x 64(f) x 64(k)
__global__ __launch_bounds__(256) void gemm_mfma_partial(const ushort_t* __restrict__ xbf,
                                                         const float* __restrict__ W,
                                                         float* __restrict__ part) {
  __shared__ ushort_t xs[2][128 * 64];
  __shared__ ushort_t wsl[2][64 * 64];
  const int f0 = blockIdx.x * 64;
  const int kc = blockIdx.y;
  const int tid = threadIdx.x;
  const int w = tid >> 6, lane = tid & 63;

  f32x4 acc[2][4];
#pragma unroll
  for (int i = 0; i < 2; ++i)
#pragma unroll
    for (int j = 0; j < 4; ++j) acc[i][j] = (f32x4){0.f, 0.f, 0.f, 0.f};

  uint4 rx[4];
  float4 rwa[2], rwb[2];
  const int kbeg = kc * 512;

#pragma unroll
  for (int l = 0; l < 4; ++l) {
    int s = tid + 256 * l, r = s >> 3, ks = s & 7;
    rx[l] = *(const uint4*)(xbf + (size_t)r * 4096 + kbeg + ks * 8);
  }
#pragma unroll
  for (int l = 0; l < 2; ++l) {
    int s = tid + 256 * l, r = s >> 3, ks = s & 7;
    const float* wp = W + (size_t)(f0 + r) * 4096 + kbeg + ks * 8;
    rwa[l] = *(const float4*)(wp);
    rwb[l] = *(const float4*)(wp + 4);
  }

  int cur = 0;
  for (int st = 0; st < 8; ++st) {
#pragma unroll
    for (int l = 0; l < 4; ++l) {
      int s = tid + 256 * l, r = s >> 3, ks = s & 7;
      *(uint4*)(&xs[cur][r * 64 + ((ks ^ (r & 7)) << 3)]) = rx[l];
    }
#pragma unroll
    for (int l = 0; l < 2; ++l) {
      int s = tid + 256 * l, r = s >> 3, ks = s & 7;
      uint4 pk;
      pk.x = (unsigned)f2bf(rwa[l].x) | ((unsigned)f2bf(rwa[l].y) << 16);
      pk.y = (unsigned)f2bf(rwa[l].z) | ((unsigned)f2bf(rwa[l].w) << 16);
      pk.z = (unsigned)f2bf(rwb[l].x) | ((unsigned)f2bf(rwb[l].y) << 16);
      pk.w = (unsigned)f2bf(rwb[l].z) | ((unsigned)f2bf(rwb[l].w) << 16);
      *(uint4*)(&wsl[cur][r * 64 + ((ks ^ (r & 7)) << 3)]) = pk;
    }
    __syncthreads();
    if (st < 7) {
      const int k0 = kbeg + (st + 1) * 64;
#pragma unroll
      for (int l = 0; l < 4; ++l) {
        int s = tid + 256 * l, r = s >> 3, ks = s & 7;
        rx[l] = *(const uint4*)(xbf + (size_t)r * 4096 + k0 + ks * 8);
      }
#pragma unroll
      for (int l = 0; l < 2; ++l) {
        int s = tid + 256 * l, r = s >> 3, ks = s & 7;
        const float* wp = W + (size_t)(f0 + r) * 4096 + k0 + ks * 8;
        rwa[l] = *(const float4*)(wp);
        rwb[l] = *(const float4*)(wp + 4);
      }
    }
#pragma unroll
    for (int kk = 0; kk < 2; ++kk) {
      int ksA = kk * 4 + (lane >> 4);
      short8 af[2], bfr[4];
#pragma unroll
      for (int mf = 0; mf < 2; ++mf) {
        int ra = w * 32 + mf * 16 + (lane & 15);
        af[mf] = *(const short8*)(&xs[cur][ra * 64 + ((ksA ^ (ra & 7)) << 3)]);
      }
#pragma unroll
      for (int nf = 0; nf < 4; ++nf) {
        int rb = nf * 16 + (lane & 15);
        bfr[nf] = *(const short8*)(&wsl[cur][rb * 64 + ((ksA ^ (rb & 7)) << 3)]);
      }
#pragma unroll
      for (int mf = 0; mf < 2; ++mf)
#pragma unroll
        for (int nf = 0; nf < 4; ++nf)
          acc[mf][nf] = __builtin_amdgcn_mfma_f32_16x16x32_bf16(af[mf], bfr[nf], acc[mf][nf], 0, 0, 0);
    }
    cur ^= 1;
  }
  float* pb = part + ((size_t)kc << 19);
#pragma unroll
  for (int mf = 0; mf < 2; ++mf)
#pragma unroll
    for (int nf = 0; nf < 4; ++nf)
#pragma unroll
      for (int reg = 0; reg < 4; ++reg) {
        int row = w * 32 + mf * 16 + (lane >> 4) * 4 + reg;
        int col = f0 + nf * 16 + (lane & 15);
        pb[(size_t)row * 4096 + col] = acc[mf][nf][reg];
      }
}

// ---------------- out += bias + sum of KC partials (out already holds dft_y result)
__global__ __launch_bounds__(256) void reduce_bias(const float* __restrict__ part,
                                                   const float* __restrict__ b,
                                                   float* __restrict__ out) {
  size_t e = ((size_t)blockIdx.x * 256 + threadIdx.x) * 4;
  int f = (int)(e & 4095);
  float4 o  = *(const float4*)(out + e);
  float4 bb = *(const float4*)(b + f);
  float sx = o.x + bb.x, sy = o.y + bb.y, sz = o.z + bb.z, sw = o.w + bb.w;
#pragma unroll
  for (int i = 0; i < KC; ++i) {
    float4 v = *(const float4*)(part + e + ((size_t)i << 19));
    sx += v.x; sy += v.y; sz += v.z; sw += v.w;
  }
  *(float4*)(out + e) = make_float4(sx, sy, sz, sw);
}

extern "C" void kernel_launch(void* const* d_in, const int* in_sizes, int n_in,
                              void* d_out, int out_size, void* d_ws, size_t ws_size,
                              hipStream_t stream) {
  const float* x   = (const float*)d_in[0];
  const float* W   = (const float*)d_in[1];
  const float* b   = (const float*)d_in[2];
  const float* cre = (const float*)d_in[3];
  const float* cim = (const float*)d_in[4];
  const int* midx  = (const int*)d_in[5];
  const int K = in_sizes[3];
  float* out = (float*)d_out;
  const int chunk = (K + NCHUNK - 1) / NCHUNK;

  char* ws = (char*)d_ws;
  unsigned* XTb  = (unsigned*)(ws);                        // ~1.05 MB
  float2* Y      = (float2*)(ws + (size_t)(2 << 20));      // 4 MB
  uint2* bucket  = (uint2*)(ws + (size_t)(6 << 20));       // K*8 ~= 6.7 MB (ends <13M)
  int* cnt       = (int*)(ws + (size_t)(13 << 20));        // 4 MB (ends 17M)
  char* meta     = ws + (size_t)(17 << 20);                // tot/off 32 KB
  int* tot = (int*)(meta);
  int* off = (int*)(meta + 16384);
  ushort_t* xbf  = (ushort_t*)(ws + (size_t)(18 << 20));   // 1 MB (ends 19M)
  float* part    = (float*)(ws + (size_t)(2 << 20));       // KC*2MB = 16 MB (ends 18M);
  // part ALIASES Y/bucket/cnt/meta — all fully consumed before gemm runs.

  xcvt<<<512, 256, 0, stream>>>(x, xbf);
  dft_rows_x<<<dim3(NROW, 2), 1024, 0, stream>>>(x, XTb);
  count_chunks<<<NCHUNK, 1024, 0, stream>>>(midx, K, chunk, cnt);
  colscan<<<16, 256, 0, stream>>>(cnt, tot);
  scan4096<<<1, 1024, 0, stream>>>(tot, off);
  scatter2<<<NCHUNK, 1024, 0, stream>>>(midx, cre, cim, K, chunk, cnt, off, bucket);
  spmm_col<<<2048, 256, 0, stream>>>(bucket, off, tot, XTb, Y);
  dft_rows_y<<<dim3(NROW, 2), 1024, 0, stream>>>(Y, out);      // writes out2
  gemm_mfma_partial<<<dim3(64, KC), 256, 0, stream>>>(xbf, W, part);
  reduce_bias<<<512, 256, 0, stream>>>(part, b, out);          // out += b + sum(part)
}

// Round 7
// 141.264 us; speedup vs baseline: 3.3979x; 1.0012x over previous
//
#include <hip/hip_runtime.h>

// LFMA adapter: out = x@W_base^T + b + x @ (alpha * Re(ifft2(scatter(c, mask_idx))))
// Factored: never materialize Delta_W.
//   X[t,k1] = sum_m x[t,m] e^{+2pi i m k1/4096}   (dft_rows_x; Hermitian: store k<=2048, bf16)
//   Y[t,k2] = sum_{nz (k1,k2,c)} c * X[t,k1]      (bucketed sparse, readlane-broadcast spmm)
//   out2[t,n] = SCALE * Re( sum_k2 Y[t,k2] e^{+2pi i n k2/4096} )   (dft_rows_y, WRITES out)
// R7: spmm inner loop group-8 software-pipelined (8 gathers in flight; R6's serial
// load-use chain at VGPR=32 was the 43us limiter, not occupancy).
// Bucketing: deterministic two-pass (LDS histograms + column scan), no global atomics.
// Base GEMM: kc=8 K-split, dbuf LDS, issue-early/write-late pipeline; reduce_bias sums.

#define TWO_PI 6.28318530717958647692f
constexpr int NROW = 128;
constexpr float SCALE_A = 16.0f / 16777216.0f;
constexpr int NCHUNK = 256;
constexpr int KC = 8;

typedef unsigned short ushort_t;
using short8 = __attribute__((ext_vector_type(8))) short;
using f32x4  = __attribute__((ext_vector_type(4))) float;

__device__ __forceinline__ ushort_t f2bf(float f) {
  unsigned u = __float_as_uint(f);
  u = (u + 0x7FFFu + ((u >> 16) & 1u)) >> 16;   // RNE
  return (ushort_t)u;
}

// ---------------- Kernel A: XTb[k][t] packed bf16 complex, k in [0,2048] (Hermitian).
// grid (128, 2): block qi handles k1 (mod-64 residue) in [qi*32, qi*32+32).
__global__ __launch_bounds__(1024) void dft_rows_x(const float* __restrict__ x,
                                                   unsigned* __restrict__ XTb) {
  __shared__ float xs[4096];
  __shared__ float br[2048], bi[2048];
  __shared__ float2 w64[64];
  const int t = blockIdx.x, qi = blockIdx.y, tid = threadIdx.x;
  const float* xrow = x + (size_t)t * 4096;
#pragma unroll
  for (int l = 0; l < 4; ++l) xs[tid + 1024 * l] = xrow[tid + 1024 * l];
  if (tid < 64) {
    float s, c; __sincosf(TWO_PI * (float)tid * (1.0f / 64.0f), &s, &c);
    w64[tid] = make_float2(c, s);          // W64^j = e^{+2pi i j/64}
  }
  __syncthreads();
  // phase 1: B[m1][k1] for k1 in this block's residue range only
#pragma unroll
  for (int l = 0; l < 2; ++l) {
    int o = tid + 1024 * l, m1 = o >> 5, k1l = o & 31, k1 = qi * 32 + k1l;
    float ar = 0.f, ai = 0.f;
    for (int m2 = 0; m2 < 64; ++m2) {
      float xv = xs[m1 + (m2 << 6)];
      float2 w = w64[(m2 * k1) & 63];
      ar = fmaf(xv, w.x, ar); ai = fmaf(xv, w.y, ai);
    }
    float s, c; __sincosf((float)(m1 * k1) * (TWO_PI / 4096.0f), &s, &c);
    br[(m1 << 5) + k1l] = ar * c - ai * s;
    bi[(m1 << 5) + k1l] = ar * s + ai * c;
  }
  __syncthreads();
  // phase 2: k = k1 + 64*k2, k2 in [0,32) -> covers all k<2048 with this residue
  {
    const int k1l = tid & 31, k2 = tid >> 5;
    const int k = qi * 32 + k1l + (k2 << 6);
    float xr = 0.f, xi = 0.f;
    for (int m1 = 0; m1 < 64; ++m1) {
      float brv = br[(m1 << 5) + k1l], biv = bi[(m1 << 5) + k1l];
      float2 w = w64[(m1 * k2) & 63];
      xr += brv * w.x - biv * w.y;
      xi += brv * w.y + biv * w.x;
    }
    XTb[(size_t)k * NROW + t] = (unsigned)f2bf(xr) | ((unsigned)f2bf(xi) << 16);
    if (qi == 0 && tid == 0) {             // k = 2048: w64^(32*m1) = (-1)^m1
      float xr2 = 0.f, xi2 = 0.f;
      for (int m1 = 0; m1 < 64; ++m1) {
        float sgn = (m1 & 1) ? -1.f : 1.f;
        xr2 = fmaf(sgn, br[m1 << 5], xr2);
        xi2 = fmaf(sgn, bi[m1 << 5], xi2);
      }
      XTb[(size_t)2048 * NROW + t] = (unsigned)f2bf(xr2) | ((unsigned)f2bf(xi2) << 16);
    }
  }
}

// ---------------- S1: per-chunk LDS histogram of k2
__global__ __launch_bounds__(1024) void count_chunks(const int* __restrict__ idx, int K,
                                                     int chunk, int* __restrict__ cnt) {
  __shared__ int h[4096];
  const int c = blockIdx.x, tid = threadIdx.x;
#pragma unroll
  for (int l = 0; l < 4; ++l) h[tid + 1024 * l] = 0;
  __syncthreads();
  const int j0 = c * chunk, j1 = min(j0 + chunk, K);
  for (int j = j0 + tid; j < j1; j += 1024) atomicAdd(&h[idx[j] & 4095], 1);
  __syncthreads();
#pragma unroll
  for (int l = 0; l < 4; ++l) cnt[(size_t)c * 4096 + tid + 1024 * l] = h[tid + 1024 * l];
}

// ---------------- S2: per-column exclusive scan over chunks (in place) + totals
__global__ __launch_bounds__(256) void colscan(int* __restrict__ cnt, int* __restrict__ tot) {
  const int k2 = blockIdx.x * 256 + threadIdx.x;
  int run = 0;
  for (int c8 = 0; c8 < NCHUNK; c8 += 8) {
    int v[8];
#pragma unroll
    for (int i = 0; i < 8; ++i) v[i] = cnt[(size_t)(c8 + i) * 4096 + k2];
#pragma unroll
    for (int i = 0; i < 8; ++i) {
      cnt[(size_t)(c8 + i) * 4096 + k2] = run;
      run += v[i];
    }
  }
  tot[k2] = run;
}

// ---------------- B2: exclusive scan over 4096 totals (single block)
__global__ __launch_bounds__(1024) void scan4096(const int* __restrict__ count,
                                                 int* __restrict__ off) {
  __shared__ int s[4096];
  int tid = threadIdx.x;
#pragma unroll
  for (int l = 0; l < 4; ++l) s[tid + 1024 * l] = count[tid + 1024 * l];
  __syncthreads();
  for (int d = 1; d < 4096; d <<= 1) {
    int v[4];
#pragma unroll
    for (int l = 0; l < 4; ++l) {
      int i = tid + 1024 * l;
      v[l] = s[i] + ((i >= d) ? s[i - d] : 0);
    }
    __syncthreads();
#pragma unroll
    for (int l = 0; l < 4; ++l) s[tid + 1024 * l] = v[l];
    __syncthreads();
  }
#pragma unroll
  for (int l = 0; l < 4; ++l) {
    int i = tid + 1024 * l;
    off[i] = s[i] - count[i];
  }
}

// ---------------- S3: scatter with LDS-rank (no returning global atomics)
__global__ __launch_bounds__(1024) void scatter2(const int* __restrict__ idx,
                                                 const float* __restrict__ cre,
                                                 const float* __restrict__ cim, int K,
                                                 int chunk, const int* __restrict__ base,
                                                 const int* __restrict__ off,
                                                 uint2* __restrict__ bucket) {
  __shared__ int lbase[4096];
  __shared__ int lcur[4096];
  const int c = blockIdx.x, tid = threadIdx.x;
#pragma unroll
  for (int l = 0; l < 4; ++l) {
    int k2 = tid + 1024 * l;
    lbase[k2] = base[(size_t)c * 4096 + k2] + off[k2];
    lcur[k2] = 0;
  }
  __syncthreads();
  const int j0 = c * chunk, j1 = min(j0 + chunk, K);
  for (int j = j0 + tid; j < j1; j += 1024) {
    int p = idx[j];
    int k2 = p & 4095;
    int r = atomicAdd(&lcur[k2], 1);          // LDS atomic: fast
    unsigned cr = f2bf(cre[j]), ci = f2bf(cim[j]);
    bucket[lbase[k2] + r] = make_uint2((unsigned)(p >> 12) | (cr << 16), ci << 16);
  }
}

// ---------------- B4: Y[t][k2] = sum c * X[t,k1]. 2 waves per column, 2 cols/block.
// R7: group-8 software pipeline — 8 gathers issued back-to-back before their fmas,
// entry fields (readlane results) stay in SGPRs so fold/addr math is SALU.
__global__ __launch_bounds__(256) void spmm_col(const uint2* __restrict__ bucket,
                                                const int* __restrict__ off,
                                                const int* __restrict__ count,
                                                const unsigned* __restrict__ XTb,
                                                float2* __restrict__ Y) {
  __shared__ float4 red[2][64];
  const int lane = threadIdx.x & 63;
  const int wid = threadIdx.x >> 6;
  const int colsel = wid >> 1, half = wid & 1;
  const int k2 = blockIdx.x * 2 + colsel;
  const int s = off[k2], n = count[k2];
  float ar0 = 0.f, ai0 = 0.f, ar1 = 0.f, ai1 = 0.f;
  for (int c = half * 64; c < n; c += 128) {
    int idx = c + lane;
    uint2 ec = (idx < n) ? bucket[s + idx] : make_uint2(0u, 0u);
#pragma unroll
    for (int g = 0; g < 64; g += 8) {
      uint2 xv[8];
      int crb[8], cib[8], negm[8];
#pragma unroll
      for (int u = 0; u < 8; ++u) {
        int w0 = __builtin_amdgcn_readlane((int)ec.x, g + u);
        int w1 = __builtin_amdgcn_readlane((int)ec.y, g + u);
        int k1 = w0 & 0xfff;
        negm[u] = (k1 > 2048) ? (int)0x80000000 : 0;
        int r = (k1 > 2048) ? 4096 - k1 : k1;
        crb[u] = w0 & 0xffff0000;
        cib[u] = w1;
        xv[u] = *(const uint2*)(XTb + (size_t)r * NROW + 2 * lane);
      }
#pragma unroll
      for (int u = 0; u < 8; ++u) {
        float cr  = __int_as_float(crb[u]);
        float ci  = __int_as_float(cib[u]);
        float crs = __int_as_float(crb[u] ^ negm[u]);
        float cis = __int_as_float(cib[u] ^ negm[u]);
        float xr0 = __int_as_float(xv[u].x << 16);
        float xi0 = __int_as_float(xv[u].x & 0xffff0000u);
        float xr1 = __int_as_float(xv[u].y << 16);
        float xi1 = __int_as_float(xv[u].y & 0xffff0000u);
        ar0 = fmaf(cr, xr0, ar0);  ar0 = fmaf(-cis, xi0, ar0);
        ai0 = fmaf(crs, xi0, ai0); ai0 = fmaf(ci, xr0, ai0);
        ar1 = fmaf(cr, xr1, ar1);  ar1 = fmaf(-cis, xi1, ar1);
        ai1 = fmaf(crs, xi1, ai1); ai1 = fmaf(ci, xr1, ai1);
      }
    }
  }
  if (half == 1) red[colsel][lane] = make_float4(ar0, ai0, ar1, ai1);
  __syncthreads();
  if (half == 0) {
    float4 o = red[colsel][lane];
    ar0 += o.x; ai0 += o.y; ar1 += o.z; ai1 += o.w;
    Y[(size_t)(2 * lane) * 4096 + k2]     = make_float2(ar0, ai0);
    Y[(size_t)(2 * lane + 1) * 4096 + k2] = make_float2(ar1, ai1);
  }
}

// ---------------- Kernel C: out[t][n] = SCALE * Re(DFT-4096 of Y row). grid (128,2).
// Block qi handles n1 (mod-64 residue) in [qi*32, qi*32+32). WRITES out.
__global__ __launch_bounds__(1024) void dft_rows_y(const float2* __restrict__ Y,
                                                   float* __restrict__ out) {
  __shared__ float ysr[4096], ysi[4096];
  __shared__ float br[2048], bi[2048];
  __shared__ float2 w64[64];
  const int t = blockIdx.x, qi = blockIdx.y, tid = threadIdx.x;
  const float2* yrow = Y + (size_t)t * 4096;
#pragma unroll
  for (int l = 0; l < 4; ++l) {
    float2 v = yrow[tid + 1024 * l];
    ysr[tid + 1024 * l] = v.x; ysi[tid + 1024 * l] = v.y;
  }
  if (tid < 64) {
    float s, c; __sincosf(TWO_PI * (float)tid * (1.0f / 64.0f), &s, &c);
    w64[tid] = make_float2(c, s);
  }
  __syncthreads();
  // phase 1: B[a][n1] for n1 in this block's residue range
#pragma unroll
  for (int l = 0; l < 2; ++l) {
    int o = tid + 1024 * l, a = o >> 5, n1l = o & 31, n1 = qi * 32 + n1l;
    float ar = 0.f, ai = 0.f;
    for (int b = 0; b < 64; ++b) {
      float yr = ysr[a + (b << 6)], yi = ysi[a + (b << 6)];
      float2 w = w64[(n1 * b) & 63];
      ar += yr * w.x - yi * w.y;
      ai += yr * w.y + yi * w.x;
    }
    float s, c; __sincosf((float)(n1 * a) * (TWO_PI / 4096.0f), &s, &c);
    br[(a << 5) + n1l] = ar * c - ai * s;
    bi[(a << 5) + n1l] = ar * s + ai * c;
  }
  __syncthreads();
  // phase 2: n = n1 + 64*n2, n2 in [0,64)
  float* orow = out + (size_t)t * 4096;
  const int n1l = tid & 31;
  const int n1 = qi * 32 + n1l;
#pragma unroll
  for (int l = 0; l < 2; ++l) {
    int n2 = (tid >> 5) + 32 * l;
    float acc = 0.f;
    for (int a = 0; a < 64; ++a) {
      float brv = br[(a << 5) + n1l], biv = bi[(a << 5) + n1l];
      float2 w = w64[(n2 * a) & 63];
      acc += brv * w.x - biv * w.y;
    }
    orow[n1 + (n2 << 6)] = acc * SCALE_A;
  }
}

// ---------------- x -> bf16 pre-convert
__global__ __launch_bounds__(256) void xcvt(const float* __restrict__ x,
                                            ushort_t* __restrict__ xbf) {
  size_t e = ((size_t)blockIdx.x * 256 + threadIdx.x) * 4;
  float4 v = *(const float4*)(x + e);
  unsigned lo = (unsigned)f2bf(v.x) | ((unsigned)f2bf(v.y) << 16);
  unsigned hi = (unsigned)f2bf(v.z) | ((unsigned)f2bf(v.w) << 16);
  *(uint2*)(xbf + e) = make_uint2(lo, hi);
}

// ---------------- base GEMM partials: part[kc][t][f], tile 128(t) x 64(f) x 64(k)
__global__ __launch_bounds__(256) void gemm_mfma_partial(const ushort_t* __restrict__ xbf,
                                                         const float* __restrict__ W,
                                                         float* __restrict__ part) {
  __shared__ ushort_t xs[2][128 * 64];
  __shared__ ushort_t wsl[2][64 * 64];
  const int f0 = blockIdx.x * 64;
  const int kc = blockIdx.y;
  const int tid = threadIdx.x;
  const int w = tid >> 6, lane = tid & 63;

  f32x4 acc[2][4];
#pragma unroll
  for (int i = 0; i < 2; ++i)
#pragma unroll
    for (int j = 0; j < 4; ++j) acc[i][j] = (f32x4){0.f, 0.f, 0.f, 0.f};

  uint4 rx[4];
  float4 rwa[2], rwb[2];
  const int kbeg = kc * 512;

#pragma unroll
  for (int l = 0; l < 4; ++l) {
    int s = tid + 256 * l, r = s >> 3, ks = s & 7;
    rx[l] = *(const uint4*)(xbf + (size_t)r * 4096 + kbeg + ks * 8);
  }
#pragma unroll
  for (int l = 0; l < 2; ++l) {
    int s = tid + 256 * l, r = s >> 3, ks = s & 7;
    const float* wp = W + (size_t)(f0 + r) * 4096 + kbeg + ks * 8;
    rwa[l] = *(const float4*)(wp);
    rwb[l] = *(const float4*)(wp + 4);
  }

  int cur = 0;
  for (int st = 0; st < 8; ++st) {
#pragma unroll
    for (int l = 0; l < 4; ++l) {
      int s = tid + 256 * l, r = s >> 3, ks = s & 7;
      *(uint4*)(&xs[cur][r * 64 + ((ks ^ (r & 7)) << 3)]) = rx[l];
    }
#pragma unroll
    for (int l = 0; l < 2; ++l) {
      int s = tid + 256 * l, r = s >> 3, ks = s & 7;
      uint4 pk;
      pk.x = (unsigned)f2bf(rwa[l].x) | ((unsigned)f2bf(rwa[l].y) << 16);
      pk.y = (unsigned)f2bf(rwa[l].z) | ((unsigned)f2bf(rwa[l].w) << 16);
      pk.z = (unsigned)f2bf(rwb[l].x) | ((unsigned)f2bf(rwb[l].y) << 16);
      pk.w = (unsigned)f2bf(rwb[l].z) | ((unsigned)f2bf(rwb[l].w) << 16);
      *(uint4*)(&wsl[cur][r * 64 + ((ks ^ (r & 7)) << 3)]) = pk;
    }
    __syncthreads();
    if (st < 7) {
      const int k0 = kbeg + (st + 1) * 64;
#pragma unroll
      for (int l = 0; l < 4; ++l) {
        int s = tid + 256 * l, r = s >> 3, ks = s & 7;
        rx[l] = *(const uint4*)(xbf + (size_t)r * 4096 + k0 + ks * 8);
      }
#pragma unroll
      for (int l = 0; l < 2; ++l) {
        int s = tid + 256 * l, r = s >> 3, ks = s & 7;
        const float* wp = W + (size_t)(f0 + r) * 4096 + k0 + ks * 8;
        rwa[l] = *(const float4*)(wp);
        rwb[l] = *(const float4*)(wp + 4);
      }
    }
#pragma unroll
    for (int kk = 0; kk < 2; ++kk) {
      int ksA = kk * 4 + (lane >> 4);
      short8 af[2], bfr[4];
#pragma unroll
      for (int mf = 0; mf < 2; ++mf) {
        int ra = w * 32 + mf * 16 + (lane & 15);
        af[mf] = *(const short8*)(&xs[cur][ra * 64 + ((ksA ^ (ra & 7)) << 3)]);
      }
#pragma unroll
      for (int nf = 0; nf < 4; ++nf) {
        int rb = nf * 16 + (lane & 15);
        bfr[nf] = *(const short8*)(&wsl[cur][rb * 64 + ((ksA ^ (rb & 7)) << 3)]);
      }
#pragma unroll
      for (int mf = 0; mf < 2; ++mf)
#pragma unroll
        for (int nf = 0; nf < 4; ++nf)
          acc[mf][nf] = __builtin_amdgcn_mfma_f32_16x16x32_bf16(af[mf], bfr[nf], acc[mf][nf], 0, 0, 0);
    }
    cur ^= 1;
  }
  float* pb = part + ((size_t)kc << 19);
#pragma unroll
  for (int mf = 0; mf < 2; ++mf)
#pragma unroll
    for (int nf = 0; nf < 4; ++nf)
#pragma unroll
      for (int reg = 0; reg < 4; ++reg) {
        int row = w * 32 + mf * 16 + (lane >> 4) * 4 + reg;
        int col = f0 + nf * 16 + (lane & 15);
        pb[(size_t)row * 4096 + col] = acc[mf][nf][reg];
      }
}

// ---------------- out += bias + sum of KC partials (out already holds dft_y result)
__global__ __launch_bounds__(256) void reduce_bias(const float* __restrict__ part,
                                                   const float* __restrict__ b,
                                                   float* __restrict__ out) {
  size_t e = ((size_t)blockIdx.x * 256 + threadIdx.x) * 4;
  int f = (int)(e & 4095);
  float4 o  = *(const float4*)(out + e);
  float4 bb = *(const float4*)(b + f);
  float sx = o.x + bb.x, sy = o.y + bb.y, sz = o.z + bb.z, sw = o.w + bb.w;
#pragma unroll
  for (int i = 0; i < KC; ++i) {
    float4 v = *(const float4*)(part + e + ((size_t)i << 19));
    sx += v.x; sy += v.y; sz += v.z; sw += v.w;
  }
  *(float4*)(out + e) = make_float4(sx, sy, sz, sw);
}

extern "C" void kernel_launch(void* const* d_in, const int* in_sizes, int n_in,
                              void* d_out, int out_size, void* d_ws, size_t ws_size,
                              hipStream_t stream) {
  const float* x   = (const float*)d_in[0];
  const float* W   = (const float*)d_in[1];
  const float* b   = (const float*)d_in[2];
  const float* cre = (const float*)d_in[3];
  const float* cim = (const float*)d_in[4];
  const int* midx  = (const int*)d_in[5];
  const int K = in_sizes[3];
  float* out = (float*)d_out;
  const int chunk = (K + NCHUNK - 1) / NCHUNK;

  char* ws = (char*)d_ws;
  unsigned* XTb  = (unsigned*)(ws);                        // ~1.05 MB
  float2* Y      = (float2*)(ws + (size_t)(2 << 20));      // 4 MB
  uint2* bucket  = (uint2*)(ws + (size_t)(6 << 20));       // K*8 ~= 6.7 MB (ends <13M)
  int* cnt       = (int*)(ws + (size_t)(13 << 20));        // 4 MB (ends 17M)
  char* meta     = ws + (size_t)(17 << 20);                // tot/off 32 KB
  int* tot = (int*)(meta);
  int* off = (int*)(meta + 16384);
  ushort_t* xbf  = (ushort_t*)(ws + (size_t)(18 << 20));   // 1 MB (ends 19M)
  float* part    = (float*)(ws + (size_t)(2 << 20));       // KC*2MB = 16 MB (ends 18M);
  // part ALIASES Y/bucket/cnt/meta — all fully consumed before gemm runs.

  xcvt<<<512, 256, 0, stream>>>(x, xbf);
  dft_rows_x<<<dim3(NROW, 2), 1024, 0, stream>>>(x, XTb);
  count_chunks<<<NCHUNK, 1024, 0, stream>>>(midx, K, chunk, cnt);
  colscan<<<16, 256, 0, stream>>>(cnt, tot);
  scan4096<<<1, 1024, 0, stream>>>(tot, off);
  scatter2<<<NCHUNK, 1024, 0, stream>>>(midx, cre, cim, K, chunk, cnt, off, bucket);
  spmm_col<<<2048, 256, 0, stream>>>(bucket, off, tot, XTb, Y);
  dft_rows_y<<<dim3(NROW, 2), 1024, 0, stream>>>(Y, out);      // writes out2
  gemm_mfma_partial<<<dim3(64, KC), 256, 0, stream>>>(xbf, W, part);
  reduce_bias<<<512, 256, 0, stream>>>(part, b, out);          // out += b + sum(part)
}